// Round 1
// baseline (751.920 us; speedup 1.0000x reference)
//
#include <hip/hip_runtime.h>
#include <hip/hip_bf16.h>
#include <math.h>

#define D 256
#define D_SEQ 1280
#define D_HEAD 48
#define N_HEAD 8
#define HDH 384        // N_HEAD * D_HEAD
#define N_NODE 2048
#define B_GRAPH 8
#define S_LEN 1024
#define LN_EPS 1e-5f
#define INV_SCALE 0.14433756729740643f   // 1/sqrt(48)

// ---------------------------------------------------------------------------
// ranges: lower_bound of each graph id in the (sorted) batch array
// ---------------------------------------------------------------------------
__global__ void ranges_kernel(const int* __restrict__ batch, int* __restrict__ ranges) {
    int t = threadIdx.x;
    if (t <= B_GRAPH) {
        int lo = 0, hi = N_NODE;
        while (lo < hi) {
            int mid = (lo + hi) >> 1;
            if (batch[mid] < t) lo = mid + 1; else hi = mid;
        }
        ranges[t] = lo;
    }
}

// ---------------------------------------------------------------------------
// layernorm: one block (256 threads) per node, D == 256 (one elem per thread)
// ---------------------------------------------------------------------------
__global__ __launch_bounds__(256)
void ln_kernel(const float* __restrict__ node, const float* __restrict__ g,
               const float* __restrict__ b, float* __restrict__ y) {
    int n = blockIdx.x, t = threadIdx.x;
    float x = node[n * D + t];
    float s = x, sq = x * x;
    #pragma unroll
    for (int o = 32; o > 0; o >>= 1) {
        s  += __shfl_down(s, o);
        sq += __shfl_down(sq, o);
    }
    __shared__ float ss[4], sqs[4];
    if ((t & 63) == 0) { ss[t >> 6] = s; sqs[t >> 6] = sq; }
    __syncthreads();
    float S  = ss[0] + ss[1] + ss[2] + ss[3];
    float SQ = sqs[0] + sqs[1] + sqs[2] + sqs[3];
    float mu  = S * (1.f / D);
    float var = SQ * (1.f / D) - mu * mu;
    float inv = rsqrtf(var + LN_EPS);
    y[n * D + t] = (x - mu) * inv * g[t] + b[t];
}

// ---------------------------------------------------------------------------
// generic fp32 GEMM: C[M,N] = act( (A[M,K] @ B[K,N]) * scale + bias ) + resid
// 64x64 tile per 256-thread block, 4x4 per thread, K-tile = 16.
// Requires M%64==0, N%64==0, K%16==0 (true for all call sites here).
// act: 0 = none, 1 = sigmoid
// ---------------------------------------------------------------------------
__global__ __launch_bounds__(256)
void gemm64(const float* __restrict__ A, const float* __restrict__ B,
            float* __restrict__ C, int M, int N, int K,
            const float* __restrict__ bias, const float* __restrict__ resid,
            float scale, int act) {
    __shared__ float As[16][68];   // [k][m], pad 68 keeps float4 alignment
    __shared__ float Bs[16][68];   // [k][n]
    const int tid = threadIdx.x;
    const int tx = tid & 15, ty = tid >> 4;
    const int m0 = blockIdx.y * 64, n0 = blockIdx.x * 64;
    float c[4][4] = {};

    const int ka = tid & 15, ma = tid >> 4;   // A-tile load coords
    const int nb = tid & 63, kb = tid >> 6;   // B-tile load coords

    for (int k0 = 0; k0 < K; k0 += 16) {
        #pragma unroll
        for (int i = 0; i < 4; ++i)
            As[ka][ma + 16 * i] = A[(size_t)(m0 + ma + 16 * i) * K + k0 + ka];
        #pragma unroll
        for (int i = 0; i < 4; ++i)
            Bs[kb + 4 * i][nb] = B[(size_t)(k0 + kb + 4 * i) * N + n0 + nb];
        __syncthreads();
        #pragma unroll
        for (int kk = 0; kk < 16; ++kk) {
            float4 av = *(const float4*)&As[kk][ty * 4];
            float4 bv = *(const float4*)&Bs[kk][tx * 4];
            float a[4] = {av.x, av.y, av.z, av.w};
            float bb[4] = {bv.x, bv.y, bv.z, bv.w};
            #pragma unroll
            for (int i = 0; i < 4; ++i)
                #pragma unroll
                for (int j = 0; j < 4; ++j)
                    c[i][j] += a[i] * bb[j];
        }
        __syncthreads();
    }

    #pragma unroll
    for (int i = 0; i < 4; ++i) {
        int m = m0 + ty * 4 + i;
        #pragma unroll
        for (int j = 0; j < 4; ++j) {
            int n = n0 + tx * 4 + j;
            float v = c[i][j] * scale;
            if (bias)  v += bias[n];
            if (act == 1) v = 1.f / (1.f + __expf(-v));
            if (resid) v += resid[(size_t)m * N + n];
            C[(size_t)m * N + n] = v;
        }
    }
}

// ---------------------------------------------------------------------------
// attention: block = (16-node tile within graph, head, graph). 256 threads.
// thread (r = tid&15, g = tid>>4) owns node r, dims {g, g+16, g+32}.
// Streams S in chunks of 128 through LDS, online softmax, fused gate.
// ---------------------------------------------------------------------------
#define CH 128
__global__ __launch_bounds__(256)
void attn_kernel(const float* __restrict__ q, const float* __restrict__ kk,
                 const float* __restrict__ vv, const int* __restrict__ mask,
                 const float* __restrict__ gate, const int* __restrict__ ranges,
                 float* __restrict__ gfeat) {
    __shared__ float qs[16][50];      // pad 50 -> conflict-free strided reads
    __shared__ float ks[CH][50];
    __shared__ float vs[CH][50];
    __shared__ float ps[CH][16];
    __shared__ float red[16][17];
    __shared__ float mk[CH];

    const int b = blockIdx.z, h = blockIdx.y, tile = blockIdx.x;
    const int nstart = ranges[b], nend = ranges[b + 1];
    const int n0 = nstart + tile * 16;
    if (n0 >= nend) return;
    const int NT = min(16, nend - n0);

    const int tid = threadIdx.x;
    const int r = tid & 15, g = tid >> 4;

    for (int idx = tid; idx < 16 * 48; idx += 256) {
        int rr = idx / 48, dd = idx % 48;
        qs[rr][dd] = (rr < NT) ? q[(size_t)(n0 + rr) * HDH + h * D_HEAD + dd] : 0.f;
    }

    float m_i = -1e30f, l_i = 0.f;
    float acc0 = 0.f, acc1 = 0.f, acc2 = 0.f;

    for (int s0 = 0; s0 < S_LEN; s0 += CH) {
        __syncthreads();   // protect ks/vs/ps/mk/red from previous readers
        for (int idx = tid; idx < CH * 48; idx += 256) {
            int ssn = idx / 48, dd = idx % 48;
            size_t row = (size_t)(b * S_LEN + s0 + ssn) * HDH + h * D_HEAD + dd;
            ks[ssn][dd] = kk[row];
            vs[ssn][dd] = vv[row];
        }
        if (tid < CH) mk[tid] = (float)mask[b * S_LEN + s0 + tid];
        __syncthreads();

        // scores for this thread: s indices g + 16j
        float pv[8];
        float cm = -1e30f;
        #pragma unroll
        for (int j = 0; j < 8; ++j) {
            int sc = g + j * 16;
            float dot = 0.f;
            #pragma unroll
            for (int dd = 0; dd < 48; ++dd) dot += qs[r][dd] * ks[sc][dd];
            float sv = (mk[sc] > 0.f) ? dot : -1e30f;   // q pre-scaled by 1/sqrt(48)
            pv[j] = sv;
            cm = fmaxf(cm, sv);
        }
        red[g][r] = cm;
        __syncthreads();
        float m_c = -1e30f;
        #pragma unroll
        for (int gg = 0; gg < 16; ++gg) m_c = fmaxf(m_c, red[gg][r]);
        float m_new = fmaxf(m_i, m_c);
        float alpha = __expf(m_i - m_new);
        float ls = 0.f;
        #pragma unroll
        for (int j = 0; j < 8; ++j) {
            int sc = g + j * 16;
            float p = (mk[sc] > 0.f) ? __expf(pv[j] - m_new) : 0.f;
            ps[sc][r] = p;
            ls += p;
        }
        m_i = m_new;
        __syncthreads();   // ps fully written; red reads (m_c) done
        red[g][r] = ls;
        __syncthreads();
        float lsum = 0.f;
        #pragma unroll
        for (int gg = 0; gg < 16; ++gg) lsum += red[gg][r];
        l_i = l_i * alpha + lsum;

        acc0 *= alpha; acc1 *= alpha; acc2 *= alpha;
        #pragma unroll 4
        for (int sc = 0; sc < CH; ++sc) {
            float p = ps[sc][r];
            acc0 += p * vs[sc][g];
            acc1 += p * vs[sc][g + 16];
            acc2 += p * vs[sc][g + 32];
        }
    }

    if (r < NT) {
        float invl = 1.f / (l_i + 1e-9f);
        size_t base = (size_t)(n0 + r) * HDH + h * D_HEAD;
        gfeat[base + g]      = gate[base + g]      * acc0 * invl;
        gfeat[base + g + 16] = gate[base + g + 16] * acc1 * invl;
        gfeat[base + g + 32] = gate[base + g + 32] * acc2 * invl;
    }
}

// ---------------------------------------------------------------------------
extern "C" void kernel_launch(void* const* d_in, const int* in_sizes, int n_in,
                              void* d_out, int out_size, void* d_ws, size_t ws_size,
                              hipStream_t stream) {
    const float* node  = (const float*)d_in[0];
    const float* emb   = (const float*)d_in[1];
    const int*   mask  = (const int*)d_in[2];
    const int*   batch = (const int*)d_in[3];
    const float* ln_g  = (const float*)d_in[4];
    const float* ln_b  = (const float*)d_in[5];
    const float* Wq    = (const float*)d_in[6];
    const float* Wk    = (const float*)d_in[7];
    const float* Wv    = (const float*)d_in[8];
    const float* Wg    = (const float*)d_in[9];
    const float* bg    = (const float*)d_in[10];
    const float* Wback = (const float*)d_in[11];
    const float* bback = (const float*)d_in[12];
    float* out = (float*)d_out;

    float* ws    = (float*)d_ws;
    float* y     = ws;                           // 2048*256
    float* q     = y + (size_t)N_NODE * D;       // 2048*384
    float* gate  = q + (size_t)N_NODE * HDH;     // 2048*384
    float* kkw   = gate + (size_t)N_NODE * HDH;  // 8192*384
    float* vvw   = kkw + (size_t)B_GRAPH * S_LEN * HDH;
    float* gfeat = vvw + (size_t)B_GRAPH * S_LEN * HDH;  // 2048*384
    int*   ranges = (int*)(gfeat + (size_t)N_NODE * HDH);

    ranges_kernel<<<1, 64, 0, stream>>>(batch, ranges);
    ln_kernel<<<N_NODE, 256, 0, stream>>>(node, ln_g, ln_b, y);
    // q = (y @ Wq) / sqrt(Dh)
    gemm64<<<dim3(HDH / 64, N_NODE / 64), 256, 0, stream>>>(
        y, Wq, q, N_NODE, HDH, D, nullptr, nullptr, INV_SCALE, 0);
    // gate = sigmoid(y @ Wg + bg)
    gemm64<<<dim3(HDH / 64, N_NODE / 64), 256, 0, stream>>>(
        y, Wg, gate, N_NODE, HDH, D, bg, nullptr, 1.f, 1);
    // k = emb @ Wk ; v = emb @ Wv   (emb flattened [8192, 1280])
    gemm64<<<dim3(HDH / 64, (B_GRAPH * S_LEN) / 64), 256, 0, stream>>>(
        emb, Wk, kkw, B_GRAPH * S_LEN, HDH, D_SEQ, nullptr, nullptr, 1.f, 0);
    gemm64<<<dim3(HDH / 64, (B_GRAPH * S_LEN) / 64), 256, 0, stream>>>(
        emb, Wv, vvw, B_GRAPH * S_LEN, HDH, D_SEQ, nullptr, nullptr, 1.f, 0);
    // attention + gate fuse -> gfeat
    attn_kernel<<<dim3(128, N_HEAD, B_GRAPH), 256, 0, stream>>>(
        q, kkw, vvw, mask, gate, ranges, gfeat);
    // out = node + gfeat @ Wback + bback
    gemm64<<<dim3(D / 64, N_NODE / 64), 256, 0, stream>>>(
        gfeat, Wback, out, N_NODE, D, HDH, bback, node, 1.f, 0);
}

// Round 2
// 560.141 us; speedup vs baseline: 1.3424x; 1.3424x over previous
//
#include <hip/hip_runtime.h>
#include <hip/hip_bf16.h>
#include <math.h>

#define D 256
#define D_SEQ 1280
#define D_HEAD 48
#define N_HEAD 8
#define HDH 384        // N_HEAD * D_HEAD
#define N_NODE 2048
#define B_GRAPH 8
#define S_LEN 1024
#define LN_EPS 1e-5f
#define INV_SCALE 0.14433756729740643f   // 1/sqrt(48)
#define KVN 768        // fused K|V output width (cols 0..383 = K, 384..767 = V)

typedef unsigned short u16;
typedef __attribute__((ext_vector_type(8))) short short8;
typedef __attribute__((ext_vector_type(4))) float floatx4;

__device__ __forceinline__ u16 f2bf(float f) {
    unsigned int x = __float_as_uint(f);
    x += 0x7fff + ((x >> 16) & 1);      // RNE to bf16
    return (u16)(x >> 16);
}

// ---------------------------------------------------------------------------
// ranges: lower_bound of each graph id in the (sorted) batch array
// ---------------------------------------------------------------------------
__global__ void ranges_kernel(const int* __restrict__ batch, int* __restrict__ ranges) {
    int t = threadIdx.x;
    if (t <= B_GRAPH) {
        int lo = 0, hi = N_NODE;
        while (lo < hi) {
            int mid = (lo + hi) >> 1;
            if (batch[mid] < t) lo = mid + 1; else hi = mid;
        }
        ranges[t] = lo;
    }
}

// ---------------------------------------------------------------------------
// layernorm: one block (256 threads) per node, D == 256
// ---------------------------------------------------------------------------
__global__ __launch_bounds__(256)
void ln_kernel(const float* __restrict__ node, const float* __restrict__ g,
               const float* __restrict__ b, float* __restrict__ y) {
    int n = blockIdx.x, t = threadIdx.x;
    float x = node[n * D + t];
    float s = x, sq = x * x;
    #pragma unroll
    for (int o = 32; o > 0; o >>= 1) {
        s  += __shfl_down(s, o);
        sq += __shfl_down(sq, o);
    }
    __shared__ float ss[4], sqs[4];
    if ((t & 63) == 0) { ss[t >> 6] = s; sqs[t >> 6] = sq; }
    __syncthreads();
    float S  = ss[0] + ss[1] + ss[2] + ss[3];
    float SQ = sqs[0] + sqs[1] + sqs[2] + sqs[3];
    float mu  = S * (1.f / D);
    float var = SQ * (1.f / D) - mu * mu;
    float inv = rsqrtf(var + LN_EPS);
    y[n * D + t] = (x - mu) * inv * g[t] + b[t];
}

// ---------------------------------------------------------------------------
// weight transpose+convert: WT[768][1280] bf16; rows 0..383 = Wk^T, 384..767 = Wv^T
// Wk/Wv are [1280][384] fp32. Write-coalesced over k.
// ---------------------------------------------------------------------------
__global__ __launch_bounds__(256)
void wt_kernel(const float* __restrict__ Wk, const float* __restrict__ Wv,
               u16* __restrict__ WT) {
    int k = blockIdx.x * 256 + threadIdx.x;   // 0..1279
    int n = blockIdx.y;                        // 0..767
    float v = (n < HDH) ? Wk[(size_t)k * HDH + n] : Wv[(size_t)k * HDH + (n - HDH)];
    WT[(size_t)n * D_SEQ + k] = f2bf(v);
}

// ---------------------------------------------------------------------------
// fused K|V projection: C[8192][768] = emb[8192][1280] @ WT[768][1280]^T
// bf16 MFMA 16x16x32, 128x128 tile, BK=32, 4 waves (2x2, 64x64 each, 4x4 tiles).
// A (emb) is fp32 in global, converted to bf16 during LDS staging.
// Verified fragment maps: A[m=lane&15][k=(lane>>4)*8+j]; C/D col=lane&15,
// row=(lane>>4)*4+reg  [learn_hip m89].
// ---------------------------------------------------------------------------
__global__ __launch_bounds__(256)
void kv_gemm(const float* __restrict__ A, const u16* __restrict__ WT,
             float* __restrict__ C) {
    __shared__ __align__(16) u16 As[128 * 32];
    __shared__ __align__(16) u16 Bs[128 * 32];
    const int tid = threadIdx.x;
    const int lane = tid & 63, wave = tid >> 6;
    const int wm = (wave >> 1) * 64, wn = (wave & 1) * 64;
    const int m0 = blockIdx.y * 128, n0 = blockIdx.x * 128;
    const int lm = lane & 15, lq = lane >> 4;

    floatx4 acc[4][4] = {};

    const int sr = tid >> 2;          // staging row 0..63 (and +64)
    const int sc = (tid & 3) * 8;     // staging col {0,8,16,24}

    for (int k0 = 0; k0 < D_SEQ; k0 += 32) {
        // global loads first (overlap with barrier)
        const float4 a0 = *(const float4*)&A[(size_t)(m0 + sr) * D_SEQ + k0 + sc];
        const float4 a1 = *(const float4*)&A[(size_t)(m0 + sr) * D_SEQ + k0 + sc + 4];
        const float4 a2 = *(const float4*)&A[(size_t)(m0 + sr + 64) * D_SEQ + k0 + sc];
        const float4 a3 = *(const float4*)&A[(size_t)(m0 + sr + 64) * D_SEQ + k0 + sc + 4];
        const int4  b0 = *(const int4*)&WT[(size_t)(n0 + sr) * D_SEQ + k0 + sc];
        const int4  b1 = *(const int4*)&WT[(size_t)(n0 + sr + 64) * D_SEQ + k0 + sc];
        __syncthreads();   // previous iteration's frag reads done
        {
            union { u16 u[8]; int4 v; } p;
            p.u[0]=f2bf(a0.x); p.u[1]=f2bf(a0.y); p.u[2]=f2bf(a0.z); p.u[3]=f2bf(a0.w);
            p.u[4]=f2bf(a1.x); p.u[5]=f2bf(a1.y); p.u[6]=f2bf(a1.z); p.u[7]=f2bf(a1.w);
            *(int4*)&As[sr * 32 + sc] = p.v;
        }
        {
            union { u16 u[8]; int4 v; } p;
            p.u[0]=f2bf(a2.x); p.u[1]=f2bf(a2.y); p.u[2]=f2bf(a2.z); p.u[3]=f2bf(a2.w);
            p.u[4]=f2bf(a3.x); p.u[5]=f2bf(a3.y); p.u[6]=f2bf(a3.z); p.u[7]=f2bf(a3.w);
            *(int4*)&As[(sr + 64) * 32 + sc] = p.v;
        }
        *(int4*)&Bs[sr * 32 + sc] = b0;
        *(int4*)&Bs[(sr + 64) * 32 + sc] = b1;
        __syncthreads();

        short8 af[4], bfr[4];
        #pragma unroll
        for (int i = 0; i < 4; ++i)
            af[i] = *(const short8*)&As[(wm + i * 16 + lm) * 32 + lq * 8];
        #pragma unroll
        for (int i = 0; i < 4; ++i)
            bfr[i] = *(const short8*)&Bs[(wn + i * 16 + lm) * 32 + lq * 8];
        #pragma unroll
        for (int i = 0; i < 4; ++i)
            #pragma unroll
            for (int j = 0; j < 4; ++j)
                acc[i][j] = __builtin_amdgcn_mfma_f32_16x16x32_bf16(
                    af[i], bfr[j], acc[i][j], 0, 0, 0);
    }

    #pragma unroll
    for (int i = 0; i < 4; ++i)
        #pragma unroll
        for (int j = 0; j < 4; ++j)
            #pragma unroll
            for (int r = 0; r < 4; ++r) {
                int m = m0 + wm + i * 16 + lq * 4 + r;
                int n = n0 + wn + j * 16 + lm;
                C[(size_t)m * KVN + n] = acc[i][j][r];
            }
}

// ---------------------------------------------------------------------------
// generic fp32 GEMM (unchanged): 64x64 tile, used for q/gate/back projections
// ---------------------------------------------------------------------------
__global__ __launch_bounds__(256)
void gemm64(const float* __restrict__ A, const float* __restrict__ B,
            float* __restrict__ C, int M, int N, int K,
            const float* __restrict__ bias, const float* __restrict__ resid,
            float scale, int act) {
    __shared__ float Asm[16][68];
    __shared__ float Bsm[16][68];
    const int tid = threadIdx.x;
    const int tx = tid & 15, ty = tid >> 4;
    const int m0 = blockIdx.y * 64, n0 = blockIdx.x * 64;
    float c[4][4] = {};

    const int ka = tid & 15, ma = tid >> 4;
    const int nb = tid & 63, kb = tid >> 6;

    for (int k0 = 0; k0 < K; k0 += 16) {
        #pragma unroll
        for (int i = 0; i < 4; ++i)
            Asm[ka][ma + 16 * i] = A[(size_t)(m0 + ma + 16 * i) * K + k0 + ka];
        #pragma unroll
        for (int i = 0; i < 4; ++i)
            Bsm[kb + 4 * i][nb] = B[(size_t)(k0 + kb + 4 * i) * N + n0 + nb];
        __syncthreads();
        #pragma unroll
        for (int kk = 0; kk < 16; ++kk) {
            float4 av = *(const float4*)&Asm[kk][ty * 4];
            float4 bv = *(const float4*)&Bsm[kk][tx * 4];
            float a[4] = {av.x, av.y, av.z, av.w};
            float bb[4] = {bv.x, bv.y, bv.z, bv.w};
            #pragma unroll
            for (int i = 0; i < 4; ++i)
                #pragma unroll
                for (int j = 0; j < 4; ++j)
                    c[i][j] += a[i] * bb[j];
        }
        __syncthreads();
    }

    #pragma unroll
    for (int i = 0; i < 4; ++i) {
        int m = m0 + ty * 4 + i;
        #pragma unroll
        for (int j = 0; j < 4; ++j) {
            int n = n0 + tx * 4 + j;
            float v = c[i][j] * scale;
            if (bias)  v += bias[n];
            if (act == 1) v = 1.f / (1.f + __expf(-v));
            if (resid) v += resid[(size_t)m * N + n];
            C[(size_t)m * N + n] = v;
        }
    }
}

// ---------------------------------------------------------------------------
// attention (unchanged except K/V now read from fused kv buffer, stride KVN)
// ---------------------------------------------------------------------------
#define CH 128
__global__ __launch_bounds__(256)
void attn_kernel(const float* __restrict__ q, const float* __restrict__ kv,
                 const int* __restrict__ mask, const float* __restrict__ gate,
                 const int* __restrict__ ranges, float* __restrict__ gfeat) {
    __shared__ float qs[16][50];
    __shared__ float ks[CH][50];
    __shared__ float vs[CH][50];
    __shared__ float ps[CH][16];
    __shared__ float red[16][17];
    __shared__ float mk[CH];

    const int b = blockIdx.z, h = blockIdx.y, tile = blockIdx.x;
    const int nstart = ranges[b], nend = ranges[b + 1];
    const int n0 = nstart + tile * 16;
    if (n0 >= nend) return;
    const int NT = min(16, nend - n0);

    const int tid = threadIdx.x;
    const int r = tid & 15, g = tid >> 4;

    for (int idx = tid; idx < 16 * 48; idx += 256) {
        int rr = idx / 48, dd = idx % 48;
        qs[rr][dd] = (rr < NT) ? q[(size_t)(n0 + rr) * HDH + h * D_HEAD + dd] : 0.f;
    }

    float m_i = -1e30f, l_i = 0.f;
    float acc0 = 0.f, acc1 = 0.f, acc2 = 0.f;

    for (int s0 = 0; s0 < S_LEN; s0 += CH) {
        __syncthreads();
        for (int idx = tid; idx < CH * 48; idx += 256) {
            int ssn = idx / 48, dd = idx % 48;
            size_t row = (size_t)(b * S_LEN + s0 + ssn) * KVN + h * D_HEAD + dd;
            ks[ssn][dd] = kv[row];
            vs[ssn][dd] = kv[row + HDH];
        }
        if (tid < CH) mk[tid] = (float)mask[b * S_LEN + s0 + tid];
        __syncthreads();

        float pv[8];
        float cm = -1e30f;
        #pragma unroll
        for (int j = 0; j < 8; ++j) {
            int sc = g + j * 16;
            float dot = 0.f;
            #pragma unroll
            for (int dd = 0; dd < 48; ++dd) dot += qs[r][dd] * ks[sc][dd];
            float sv = (mk[sc] > 0.f) ? dot : -1e30f;
            pv[j] = sv;
            cm = fmaxf(cm, sv);
        }
        red[g][r] = cm;
        __syncthreads();
        float m_c = -1e30f;
        #pragma unroll
        for (int gg = 0; gg < 16; ++gg) m_c = fmaxf(m_c, red[gg][r]);
        float m_new = fmaxf(m_i, m_c);
        float alpha = __expf(m_i - m_new);
        float ls = 0.f;
        #pragma unroll
        for (int j = 0; j < 8; ++j) {
            int sc = g + j * 16;
            float p = (mk[sc] > 0.f) ? __expf(pv[j] - m_new) : 0.f;
            ps[sc][r] = p;
            ls += p;
        }
        m_i = m_new;
        __syncthreads();
        red[g][r] = ls;
        __syncthreads();
        float lsum = 0.f;
        #pragma unroll
        for (int gg = 0; gg < 16; ++gg) lsum += red[gg][r];
        l_i = l_i * alpha + lsum;

        acc0 *= alpha; acc1 *= alpha; acc2 *= alpha;
        #pragma unroll 4
        for (int sc = 0; sc < CH; ++sc) {
            float p = ps[sc][r];
            acc0 += p * vs[sc][g];
            acc1 += p * vs[sc][g + 16];
            acc2 += p * vs[sc][g + 32];
        }
    }

    if (r < NT) {
        float invl = 1.f / (l_i + 1e-9f);
        size_t base = (size_t)(n0 + r) * HDH + h * D_HEAD;
        gfeat[base + g]      = gate[base + g]      * acc0 * invl;
        gfeat[base + g + 16] = gate[base + g + 16] * acc1 * invl;
        gfeat[base + g + 32] = gate[base + g + 32] * acc2 * invl;
    }
}

// ---------------------------------------------------------------------------
extern "C" void kernel_launch(void* const* d_in, const int* in_sizes, int n_in,
                              void* d_out, int out_size, void* d_ws, size_t ws_size,
                              hipStream_t stream) {
    const float* node  = (const float*)d_in[0];
    const float* emb   = (const float*)d_in[1];
    const int*   mask  = (const int*)d_in[2];
    const int*   batch = (const int*)d_in[3];
    const float* ln_g  = (const float*)d_in[4];
    const float* ln_b  = (const float*)d_in[5];
    const float* Wq    = (const float*)d_in[6];
    const float* Wk    = (const float*)d_in[7];
    const float* Wv    = (const float*)d_in[8];
    const float* Wg    = (const float*)d_in[9];
    const float* bg    = (const float*)d_in[10];
    const float* Wback = (const float*)d_in[11];
    const float* bback = (const float*)d_in[12];
    float* out = (float*)d_out;

    float* ws    = (float*)d_ws;
    float* y     = ws;                                    // 2048*256
    float* q     = y + (size_t)N_NODE * D;                // 2048*384
    float* gate  = q + (size_t)N_NODE * HDH;              // 2048*384
    float* kvb   = gate + (size_t)N_NODE * HDH;           // 8192*768
    float* gfeat = kvb + (size_t)B_GRAPH * S_LEN * KVN;   // 2048*384
    u16*   WT    = (u16*)(gfeat + (size_t)N_NODE * HDH);  // 768*1280 bf16
    int*   ranges = (int*)(WT + (size_t)KVN * D_SEQ);

    ranges_kernel<<<1, 64, 0, stream>>>(batch, ranges);
    ln_kernel<<<N_NODE, 256, 0, stream>>>(node, ln_g, ln_b, y);
    // weights -> bf16, transposed, fused [K|V]
    wt_kernel<<<dim3(D_SEQ / 256, KVN), 256, 0, stream>>>(Wk, Wv, WT);
    // fused K|V projection via MFMA
    kv_gemm<<<dim3(KVN / 128, (B_GRAPH * S_LEN) / 128), 256, 0, stream>>>(emb, WT, kvb);
    // q = (y @ Wq) / sqrt(Dh)
    gemm64<<<dim3(HDH / 64, N_NODE / 64), 256, 0, stream>>>(
        y, Wq, q, N_NODE, HDH, D, nullptr, nullptr, INV_SCALE, 0);
    // gate = sigmoid(y @ Wg + bg)
    gemm64<<<dim3(HDH / 64, N_NODE / 64), 256, 0, stream>>>(
        y, Wg, gate, N_NODE, HDH, D, bg, nullptr, 1.f, 1);
    // attention + gate fuse -> gfeat
    attn_kernel<<<dim3(128, N_HEAD, B_GRAPH), 256, 0, stream>>>(
        q, kvb, mask, gate, ranges, gfeat);
    // out = node + gfeat @ Wback + bback
    gemm64<<<dim3(D / 64, N_NODE / 64), 256, 0, stream>>>(
        gfeat, Wback, out, N_NODE, D, HDH, bback, node, 1.f, 0);
}

// Round 4
// 316.344 us; speedup vs baseline: 2.3769x; 1.7707x over previous
//
#include <hip/hip_runtime.h>
#include <hip/hip_bf16.h>
#include <math.h>

#define D 256
#define D_SEQ 1280
#define D_HEAD 48
#define N_HEAD 8
#define HDH 384        // N_HEAD * D_HEAD
#define N_NODE 2048
#define B_GRAPH 8
#define S_LEN 1024
#define LN_EPS 1e-5f
#define INV_SCALE 0.14433756729740643f   // 1/sqrt(48)
#define KVN 768        // fused K|V gemm output width
#define QROWS (N_NODE + 16)              // padded Q rows per head

typedef unsigned short u16;
typedef __attribute__((ext_vector_type(8))) short short8;
typedef __attribute__((ext_vector_type(4))) short short4v;
typedef __attribute__((ext_vector_type(4))) unsigned short ushort4v;
typedef __attribute__((ext_vector_type(4))) float floatx4;

__device__ __forceinline__ u16 f2bf(float f) {
    unsigned int x = __float_as_uint(f);
    x += 0x7fff + ((x >> 16) & 1);      // RNE to bf16
    return (u16)(x >> 16);
}

// ---------------------------------------------------------------------------
__global__ void ranges_kernel(const int* __restrict__ batch, int* __restrict__ ranges) {
    int t = threadIdx.x;
    if (t <= B_GRAPH) {
        int lo = 0, hi = N_NODE;
        while (lo < hi) {
            int mid = (lo + hi) >> 1;
            if (batch[mid] < t) lo = mid + 1; else hi = mid;
        }
        ranges[t] = lo;
    }
}

// ---------------------------------------------------------------------------
__global__ __launch_bounds__(256)
void ln_kernel(const float* __restrict__ node, const float* __restrict__ g,
               const float* __restrict__ b, float* __restrict__ y) {
    int n = blockIdx.x, t = threadIdx.x;
    float x = node[n * D + t];
    float s = x, sq = x * x;
    #pragma unroll
    for (int o = 32; o > 0; o >>= 1) {
        s  += __shfl_down(s, o);
        sq += __shfl_down(sq, o);
    }
    __shared__ float ss[4], sqs[4];
    if ((t & 63) == 0) { ss[t >> 6] = s; sqs[t >> 6] = sq; }
    __syncthreads();
    float S  = ss[0] + ss[1] + ss[2] + ss[3];
    float SQ = sqs[0] + sqs[1] + sqs[2] + sqs[3];
    float mu  = S * (1.f / D);
    float var = SQ * (1.f / D) - mu * mu;
    float inv = rsqrtf(var + LN_EPS);
    y[n * D + t] = (x - mu) * inv * g[t] + b[t];
}

// ---------------------------------------------------------------------------
// WT[768][1280] bf16: rows 0..383 = Wk^T, 384..767 = Wv^T
// ---------------------------------------------------------------------------
__global__ __launch_bounds__(256)
void wt_kernel(const float* __restrict__ Wk, const float* __restrict__ Wv,
               u16* __restrict__ WT) {
    int k = blockIdx.x * 256 + threadIdx.x;
    int n = blockIdx.y;
    float v = (n < HDH) ? Wk[(size_t)k * HDH + n] : Wv[(size_t)k * HDH + (n - HDH)];
    WT[(size_t)n * D_SEQ + k] = f2bf(v);
}

// ---------------------------------------------------------------------------
// fused K|V projection; epilogue writes attention-ready bf16 layouts:
//   K -> Kp[b][h][s][64]   (d padded to 64; pad pre-zeroed by memset)
//   V -> VT[b][h][d][s]    (transposed, s-contiguous)
// ---------------------------------------------------------------------------
__global__ __launch_bounds__(256)
void kv_gemm(const float* __restrict__ A, const u16* __restrict__ WT,
             u16* __restrict__ Kp, u16* __restrict__ VTt) {
    __shared__ __align__(16) u16 As[128 * 32];
    __shared__ __align__(16) u16 Bs[128 * 32];
    const int tid = threadIdx.x;
    const int lane = tid & 63, wave = tid >> 6;
    const int wm = (wave >> 1) * 64, wn = (wave & 1) * 64;
    const int m0 = blockIdx.y * 128, n0 = blockIdx.x * 128;
    const int lm = lane & 15, lq = lane >> 4;

    floatx4 acc[4][4] = {};

    const int sr = tid >> 2;
    const int sc = (tid & 3) * 8;

    for (int k0 = 0; k0 < D_SEQ; k0 += 32) {
        const float4 a0 = *(const float4*)&A[(size_t)(m0 + sr) * D_SEQ + k0 + sc];
        const float4 a1 = *(const float4*)&A[(size_t)(m0 + sr) * D_SEQ + k0 + sc + 4];
        const float4 a2 = *(const float4*)&A[(size_t)(m0 + sr + 64) * D_SEQ + k0 + sc];
        const float4 a3 = *(const float4*)&A[(size_t)(m0 + sr + 64) * D_SEQ + k0 + sc + 4];
        const int4  b0 = *(const int4*)&WT[(size_t)(n0 + sr) * D_SEQ + k0 + sc];
        const int4  b1 = *(const int4*)&WT[(size_t)(n0 + sr + 64) * D_SEQ + k0 + sc];
        __syncthreads();
        {
            union { u16 u[8]; int4 v; } p;
            p.u[0]=f2bf(a0.x); p.u[1]=f2bf(a0.y); p.u[2]=f2bf(a0.z); p.u[3]=f2bf(a0.w);
            p.u[4]=f2bf(a1.x); p.u[5]=f2bf(a1.y); p.u[6]=f2bf(a1.z); p.u[7]=f2bf(a1.w);
            *(int4*)&As[sr * 32 + sc] = p.v;
        }
        {
            union { u16 u[8]; int4 v; } p;
            p.u[0]=f2bf(a2.x); p.u[1]=f2bf(a2.y); p.u[2]=f2bf(a2.z); p.u[3]=f2bf(a2.w);
            p.u[4]=f2bf(a3.x); p.u[5]=f2bf(a3.y); p.u[6]=f2bf(a3.z); p.u[7]=f2bf(a3.w);
            *(int4*)&As[(sr + 64) * 32 + sc] = p.v;
        }
        *(int4*)&Bs[sr * 32 + sc] = b0;
        *(int4*)&Bs[(sr + 64) * 32 + sc] = b1;
        __syncthreads();

        short8 af[4], bfr[4];
        #pragma unroll
        for (int i = 0; i < 4; ++i)
            af[i] = *(const short8*)&As[(wm + i * 16 + lm) * 32 + lq * 8];
        #pragma unroll
        for (int i = 0; i < 4; ++i)
            bfr[i] = *(const short8*)&Bs[(wn + i * 16 + lm) * 32 + lq * 8];
        #pragma unroll
        for (int i = 0; i < 4; ++i)
            #pragma unroll
            for (int j = 0; j < 4; ++j)
                acc[i][j] = __builtin_amdgcn_mfma_f32_16x16x32_bf16(
                    af[i], bfr[j], acc[i][j], 0, 0, 0);
    }

    // epilogue: n<384 -> K (scatter u16), n>=384 -> V^T (packed 8B)
    #pragma unroll
    for (int i = 0; i < 4; ++i) {
        const int mrow = m0 + wm + i * 16 + lq * 4;   // global emb row = b*1024+s
        const int bb = mrow >> 10, s = mrow & 1023;
        #pragma unroll
        for (int j = 0; j < 4; ++j) {
            const int n = n0 + wn + j * 16 + lm;
            if (n < HDH) {
                const int hh = n / 48, dd = n - hh * 48;
                u16* kp = &Kp[(((size_t)(bb * N_HEAD + hh)) * S_LEN + s) * 64 + dd];
                kp[0]   = f2bf(acc[i][j][0]);
                kp[64]  = f2bf(acc[i][j][1]);
                kp[128] = f2bf(acc[i][j][2]);
                kp[192] = f2bf(acc[i][j][3]);
            } else {
                const int nv = n - HDH;
                const int hh = nv / 48, dd = nv - hh * 48;
                ushort4v pk;
                pk[0] = f2bf(acc[i][j][0]); pk[1] = f2bf(acc[i][j][1]);
                pk[2] = f2bf(acc[i][j][2]); pk[3] = f2bf(acc[i][j][3]);
                *(ushort4v*)&VTt[(((size_t)(bb * N_HEAD + hh)) * 48 + dd) * S_LEN + s] = pk;
            }
        }
    }
}

// ---------------------------------------------------------------------------
// fp32 GEMM 64x64 tile. mode: 0 = C fp32 (+resid), 1 = sigmoid -> C fp32,
// 2 = write bf16 into padded Q layout qb[h][m][64] (C unused)
// ---------------------------------------------------------------------------
__global__ __launch_bounds__(256)
void gemm64(const float* __restrict__ A, const float* __restrict__ B,
            float* __restrict__ C, u16* __restrict__ qb,
            int M, int N, int K,
            const float* __restrict__ bias, const float* __restrict__ resid,
            float scale, int mode) {
    __shared__ float Asm[16][68];
    __shared__ float Bsm[16][68];
    const int tid = threadIdx.x;
    const int tx = tid & 15, ty = tid >> 4;
    const int m0 = blockIdx.y * 64, n0 = blockIdx.x * 64;
    float c[4][4] = {};

    const int ka = tid & 15, ma = tid >> 4;
    const int nb = tid & 63, kb = tid >> 6;

    for (int k0 = 0; k0 < K; k0 += 16) {
        #pragma unroll
        for (int i = 0; i < 4; ++i)
            Asm[ka][ma + 16 * i] = A[(size_t)(m0 + ma + 16 * i) * K + k0 + ka];
        #pragma unroll
        for (int i = 0; i < 4; ++i)
            Bsm[kb + 4 * i][nb] = B[(size_t)(k0 + kb + 4 * i) * N + n0 + nb];
        __syncthreads();
        #pragma unroll
        for (int kk = 0; kk < 16; ++kk) {
            float4 av = *(const float4*)&Asm[kk][ty * 4];
            float4 bv = *(const float4*)&Bsm[kk][tx * 4];
            float a[4] = {av.x, av.y, av.z, av.w};
            float bb[4] = {bv.x, bv.y, bv.z, bv.w};
            #pragma unroll
            for (int i = 0; i < 4; ++i)
                #pragma unroll
                for (int j = 0; j < 4; ++j)
                    c[i][j] += a[i] * bb[j];
        }
        __syncthreads();
    }

    #pragma unroll
    for (int i = 0; i < 4; ++i) {
        int m = m0 + ty * 4 + i;
        #pragma unroll
        for (int j = 0; j < 4; ++j) {
            int n = n0 + tx * 4 + j;
            float v = c[i][j] * scale;
            if (bias)  v += bias[n];
            if (mode == 1) v = 1.f / (1.f + __expf(-v));
            if (mode == 2) {
                int hh = n / 48, dd = n - hh * 48;
                qb[((size_t)hh * QROWS + m) * 64 + dd] = f2bf(v);
            } else {
                if (resid) v += resid[(size_t)m * N + n];
                C[(size_t)m * N + n] = v;
            }
        }
    }
}

// ---------------------------------------------------------------------------
// MFMA flash attention. Block = (16-node tile, head, graph), 4 waves,
// wave w handles s in [w*256, w*256+256). No LDS/barriers in main loop.
// S^T tile via mfma_16x16x32 (A=K[s][d], B=Q[node][d]); C: col=node, row=s.
// P^T C-frag == B-frag of mfma_16x16x16bf16_1k (k=quad*4+j) -> PV with
// A = V^T[d][s] loaded straight from global. out^T accumulated in 3 C-frags.
// ---------------------------------------------------------------------------
__global__ __launch_bounds__(256)
void attn_mfma(const u16* __restrict__ Qb, const u16* __restrict__ Kp,
               const u16* __restrict__ VTt, const int* __restrict__ mask,
               const float* __restrict__ gate, const int* __restrict__ ranges,
               float* __restrict__ gfeat) {
    const int b = blockIdx.z, h = blockIdx.y, tile = blockIdx.x;
    const int nstart = ranges[b], nend = ranges[b + 1];
    const int n0 = nstart + tile * 16;
    if (n0 >= nend) return;
    const int NT = min(16, nend - n0);

    const int tid = threadIdx.x;
    const int wave = tid >> 6, lane = tid & 63;
    const int lm = lane & 15, lq = lane >> 4;
    const int bh = b * N_HEAD + h;

    const u16* qrow = &Qb[((size_t)h * QROWS + n0 + lm) * 64];
    const short8 qf0 = *(const short8*)&qrow[lq * 8];
    const short8 qf1 = *(const short8*)&qrow[32 + lq * 8];

    const u16* kbase = &Kp[(size_t)bh * S_LEN * 64];
    const u16* vbase = &VTt[(size_t)bh * 48 * S_LEN];
    const int* mrow = &mask[b * S_LEN];

    float m_i = -1e30f, l_i = 0.f;
    floatx4 acc0 = {}, acc1 = {}, acc2 = {};

    for (int t = 0; t < 16; ++t) {
        const int s0 = wave * 256 + t * 16;
        const u16* krow = &kbase[(size_t)(s0 + lm) * 64];
        const short8 kf0 = *(const short8*)&krow[lq * 8];
        const short8 kf1 = *(const short8*)&krow[32 + lq * 8];
        floatx4 st = {};
        st = __builtin_amdgcn_mfma_f32_16x16x32_bf16(kf0, qf0, st, 0, 0, 0);
        st = __builtin_amdgcn_mfma_f32_16x16x32_bf16(kf1, qf1, st, 0, 0, 0);

        const int4 mv = *(const int4*)&mrow[s0 + lq * 4];
        const float sv0 = mv.x > 0 ? st[0] : -1e30f;
        const float sv1 = mv.y > 0 ? st[1] : -1e30f;
        const float sv2 = mv.z > 0 ? st[2] : -1e30f;
        const float sv3 = mv.w > 0 ? st[3] : -1e30f;
        float tmax = fmaxf(fmaxf(sv0, sv1), fmaxf(sv2, sv3));
        tmax = fmaxf(tmax, __shfl_xor(tmax, 16));
        tmax = fmaxf(tmax, __shfl_xor(tmax, 32));
        const float m_new = fmaxf(m_i, tmax);
        const float alpha = __expf(m_i - m_new);
        const float p0 = mv.x > 0 ? __expf(st[0] - m_new) : 0.f;
        const float p1 = mv.y > 0 ? __expf(st[1] - m_new) : 0.f;
        const float p2 = mv.z > 0 ? __expf(st[2] - m_new) : 0.f;
        const float p3 = mv.w > 0 ? __expf(st[3] - m_new) : 0.f;
        float ls = p0 + p1 + p2 + p3;
        ls += __shfl_xor(ls, 16);
        ls += __shfl_xor(ls, 32);
        m_i = m_new;
        l_i = l_i * alpha + ls;
        acc0 *= alpha; acc1 *= alpha; acc2 *= alpha;

        short4v pf;
        pf[0] = (short)f2bf(p0); pf[1] = (short)f2bf(p1);
        pf[2] = (short)f2bf(p2); pf[3] = (short)f2bf(p3);

        const int sv4 = s0 + lq * 4;
        const short4v vf0 = *(const short4v*)&vbase[(size_t)lm * S_LEN + sv4];
        const short4v vf1 = *(const short4v*)&vbase[(size_t)(16 + lm) * S_LEN + sv4];
        const short4v vf2 = *(const short4v*)&vbase[(size_t)(32 + lm) * S_LEN + sv4];
        acc0 = __builtin_amdgcn_mfma_f32_16x16x16bf16_1k(vf0, pf, acc0, 0, 0, 0);
        acc1 = __builtin_amdgcn_mfma_f32_16x16x16bf16_1k(vf1, pf, acc1, 0, 0, 0);
        acc2 = __builtin_amdgcn_mfma_f32_16x16x16bf16_1k(vf2, pf, acc2, 0, 0, 0);
    }

    // cross-wave combine
    __shared__ float sm[4][64], sl[4][64];
    __shared__ float sacc[4][3][4][64];
    sm[wave][lane] = m_i;
    sl[wave][lane] = l_i;
    #pragma unroll
    for (int r = 0; r < 4; ++r) {
        sacc[wave][0][r][lane] = acc0[r];
        sacc[wave][1][r][lane] = acc1[r];
        sacc[wave][2][r][lane] = acc2[r];
    }
    __syncthreads();
    if (wave < 3 && lm < NT) {
        const int dt = wave;
        const float M = fmaxf(fmaxf(sm[0][lane], sm[1][lane]),
                              fmaxf(sm[2][lane], sm[3][lane]));
        const float f0 = __expf(sm[0][lane] - M);
        const float f1 = __expf(sm[1][lane] - M);
        const float f2 = __expf(sm[2][lane] - M);
        const float f3 = __expf(sm[3][lane] - M);
        const float L = sl[0][lane] * f0 + sl[1][lane] * f1 +
                        sl[2][lane] * f2 + sl[3][lane] * f3;
        const float invl = 1.f / (L + 1e-9f);
        const size_t o = (size_t)(n0 + lm) * HDH + h * 48 + dt * 16 + lq * 4;
        const float4 g4 = *(const float4*)&gate[o];
        float4 ov;
        ov.x = (sacc[0][dt][0][lane] * f0 + sacc[1][dt][0][lane] * f1 +
                sacc[2][dt][0][lane] * f2 + sacc[3][dt][0][lane] * f3) * invl * g4.x;
        ov.y = (sacc[0][dt][1][lane] * f0 + sacc[1][dt][1][lane] * f1 +
                sacc[2][dt][1][lane] * f2 + sacc[3][dt][1][lane] * f3) * invl * g4.y;
        ov.z = (sacc[0][dt][2][lane] * f0 + sacc[1][dt][2][lane] * f1 +
                sacc[2][dt][2][lane] * f2 + sacc[3][dt][2][lane] * f3) * invl * g4.z;
        ov.w = (sacc[0][dt][3][lane] * f0 + sacc[1][dt][3][lane] * f1 +
                sacc[2][dt][3][lane] * f2 + sacc[3][dt][3][lane] * f3) * invl * g4.w;
        *(float4*)&gfeat[o] = ov;
    }
}

// ---------------------------------------------------------------------------
extern "C" void kernel_launch(void* const* d_in, const int* in_sizes, int n_in,
                              void* d_out, int out_size, void* d_ws, size_t ws_size,
                              hipStream_t stream) {
    const float* node  = (const float*)d_in[0];
    const float* emb   = (const float*)d_in[1];
    const int*   mask  = (const int*)d_in[2];
    const int*   batch = (const int*)d_in[3];
    const float* ln_g  = (const float*)d_in[4];
    const float* ln_b  = (const float*)d_in[5];
    const float* Wq    = (const float*)d_in[6];
    const float* Wk    = (const float*)d_in[7];
    const float* Wv    = (const float*)d_in[8];
    const float* Wg    = (const float*)d_in[9];
    const float* bg    = (const float*)d_in[10];
    const float* Wback = (const float*)d_in[11];
    const float* bback = (const float*)d_in[12];
    float* out = (float*)d_out;

    float* ws    = (float*)d_ws;
    float* y     = ws;                                     // 524288 f
    float* gate  = y + (size_t)N_NODE * D;                 // 786432 f
    float* gfeat = gate + (size_t)N_NODE * HDH;            // 786432 f
    u16*   WT    = (u16*)(gfeat + (size_t)N_NODE * HDH);   // 983040 u16
    u16*   Qb    = WT + (size_t)KVN * D_SEQ;               // 8*2064*64 u16
    u16*   Kp    = Qb + (size_t)N_HEAD * QROWS * 64;       // 64*1024*64 u16
    u16*   VTt   = Kp + (size_t)B_GRAPH * N_HEAD * S_LEN * 64;  // 64*48*1024 u16
    int*   ranges = (int*)(VTt + (size_t)B_GRAPH * N_HEAD * 48 * S_LEN);

    ranges_kernel<<<1, 64, 0, stream>>>(batch, ranges);
    ln_kernel<<<N_NODE, 256, 0, stream>>>(node, ln_g, ln_b, y);
    wt_kernel<<<dim3(D_SEQ / 256, KVN), 256, 0, stream>>>(Wk, Wv, WT);
    // zero pads (Qb rows/cols, Kp d=48..63)
    (void)hipMemsetAsync(Qb, 0, (size_t)N_HEAD * QROWS * 64 * 2, stream);
    (void)hipMemsetAsync(Kp, 0, (size_t)B_GRAPH * N_HEAD * S_LEN * 64 * 2, stream);
    // fused K|V projection -> bf16 attention layouts
    kv_gemm<<<dim3(KVN / 128, (B_GRAPH * S_LEN) / 128), 256, 0, stream>>>(
        emb, WT, Kp, VTt);
    // q (scaled, bf16 padded layout)
    gemm64<<<dim3(HDH / 64, N_NODE / 64), 256, 0, stream>>>(
        y, Wq, nullptr, Qb, N_NODE, HDH, D, nullptr, nullptr, INV_SCALE, 2);
    // gate = sigmoid(y @ Wg + bg)
    gemm64<<<dim3(HDH / 64, N_NODE / 64), 256, 0, stream>>>(
        y, Wg, gate, nullptr, N_NODE, HDH, D, bg, nullptr, 1.f, 1);
    // attention
    attn_mfma<<<dim3(128, N_HEAD, B_GRAPH), 256, 0, stream>>>(
        Qb, Kp, VTt, mask, gate, ranges, gfeat);
    // out = node + gfeat @ Wback + bback
    gemm64<<<dim3(D / 64, N_NODE / 64), 256, 0, stream>>>(
        gfeat, Wback, out, nullptr, N_NODE, D, HDH, bback, node, 1.f, 0);
}

// Round 5
// 272.082 us; speedup vs baseline: 2.7636x; 1.1627x over previous
//
#include <hip/hip_runtime.h>
#include <hip/hip_bf16.h>
#include <math.h>

#define D 256
#define D_SEQ 1280
#define D_HEAD 48
#define N_HEAD 8
#define HDH 384        // N_HEAD * D_HEAD
#define N_NODE 2048
#define B_GRAPH 8
#define S_LEN 1024
#define LN_EPS 1e-5f
#define INV_SCALE 0.14433756729740643f   // 1/sqrt(48)
#define KVN 768        // fused K|V gemm output width
#define QGN 768        // fused Q|gate gemm output width
#define QROWS (N_NODE + 16)              // padded Q rows per head

typedef unsigned short u16;
typedef __attribute__((ext_vector_type(8))) short short8;
typedef __attribute__((ext_vector_type(4))) short short4v;
typedef __attribute__((ext_vector_type(4))) unsigned short ushort4v;
typedef __attribute__((ext_vector_type(4))) float floatx4;

__device__ __forceinline__ u16 f2bf(float f) {
    unsigned int x = __float_as_uint(f);
    x += 0x7fff + ((x >> 16) & 1);      // RNE to bf16
    return (u16)(x >> 16);
}

// ---------------------------------------------------------------------------
__global__ void ranges_kernel(const int* __restrict__ batch, int* __restrict__ ranges) {
    int t = threadIdx.x;
    if (t <= B_GRAPH) {
        int lo = 0, hi = N_NODE;
        while (lo < hi) {
            int mid = (lo + hi) >> 1;
            if (batch[mid] < t) lo = mid + 1; else hi = mid;
        }
        ranges[t] = lo;
    }
}

// ---------------------------------------------------------------------------
// layernorm -> bf16 output (consumed by qg_gemm)
// ---------------------------------------------------------------------------
__global__ __launch_bounds__(256)
void ln_kernel(const float* __restrict__ node, const float* __restrict__ g,
               const float* __restrict__ b, u16* __restrict__ yb) {
    int n = blockIdx.x, t = threadIdx.x;
    float x = node[n * D + t];
    float s = x, sq = x * x;
    #pragma unroll
    for (int o = 32; o > 0; o >>= 1) {
        s  += __shfl_down(s, o);
        sq += __shfl_down(sq, o);
    }
    __shared__ float ss[4], sqs[4];
    if ((t & 63) == 0) { ss[t >> 6] = s; sqs[t >> 6] = sq; }
    __syncthreads();
    float S  = ss[0] + ss[1] + ss[2] + ss[3];
    float SQ = sqs[0] + sqs[1] + sqs[2] + sqs[3];
    float mu  = S * (1.f / D);
    float var = SQ * (1.f / D) - mu * mu;
    float inv = rsqrtf(var + LN_EPS);
    yb[n * D + t] = f2bf((x - mu) * inv * g[t] + b[t]);
}

// ---------------------------------------------------------------------------
// WT[768][1280] bf16: rows 0..383 = Wk^T, 384..767 = Wv^T
// ---------------------------------------------------------------------------
__global__ __launch_bounds__(256)
void wt_kernel(const float* __restrict__ Wk, const float* __restrict__ Wv,
               u16* __restrict__ WT) {
    int k = blockIdx.x * 256 + threadIdx.x;
    int n = blockIdx.y;
    float v = (n < HDH) ? Wk[(size_t)k * HDH + n] : Wv[(size_t)k * HDH + (n - HDH)];
    WT[(size_t)n * D_SEQ + k] = f2bf(v);
}

// ---------------------------------------------------------------------------
// WT2[768][256] bf16: rows 0..383 = Wq^T, 384..767 = Wg^T
// ---------------------------------------------------------------------------
__global__ __launch_bounds__(256)
void wt2_kernel(const float* __restrict__ Wq, const float* __restrict__ Wg,
                u16* __restrict__ WT2) {
    int k = threadIdx.x;              // 0..255
    int n = blockIdx.x;               // 0..767
    float v = (n < HDH) ? Wq[(size_t)k * HDH + n] : Wg[(size_t)k * HDH + (n - HDH)];
    WT2[(size_t)n * D + k] = f2bf(v);
}

// ---------------------------------------------------------------------------
// fused K|V projection; epilogue writes attention-ready bf16 layouts:
//   K -> Kp[b][h][s][64]   (d padded to 64; pad pre-zeroed by memset)
//   V -> VT[b][h][d][s]    (transposed, s-contiguous)
// ---------------------------------------------------------------------------
__global__ __launch_bounds__(256)
void kv_gemm(const float* __restrict__ A, const u16* __restrict__ WT,
             u16* __restrict__ Kp, u16* __restrict__ VTt) {
    __shared__ __align__(16) u16 As[128 * 32];
    __shared__ __align__(16) u16 Bs[128 * 32];
    const int tid = threadIdx.x;
    const int lane = tid & 63, wave = tid >> 6;
    const int wm = (wave >> 1) * 64, wn = (wave & 1) * 64;
    const int m0 = blockIdx.y * 128, n0 = blockIdx.x * 128;
    const int lm = lane & 15, lq = lane >> 4;

    floatx4 acc[4][4] = {};

    const int sr = tid >> 2;
    const int sc = (tid & 3) * 8;

    for (int k0 = 0; k0 < D_SEQ; k0 += 32) {
        const float4 a0 = *(const float4*)&A[(size_t)(m0 + sr) * D_SEQ + k0 + sc];
        const float4 a1 = *(const float4*)&A[(size_t)(m0 + sr) * D_SEQ + k0 + sc + 4];
        const float4 a2 = *(const float4*)&A[(size_t)(m0 + sr + 64) * D_SEQ + k0 + sc];
        const float4 a3 = *(const float4*)&A[(size_t)(m0 + sr + 64) * D_SEQ + k0 + sc + 4];
        const int4  b0 = *(const int4*)&WT[(size_t)(n0 + sr) * D_SEQ + k0 + sc];
        const int4  b1 = *(const int4*)&WT[(size_t)(n0 + sr + 64) * D_SEQ + k0 + sc];
        __syncthreads();
        {
            union { u16 u[8]; int4 v; } p;
            p.u[0]=f2bf(a0.x); p.u[1]=f2bf(a0.y); p.u[2]=f2bf(a0.z); p.u[3]=f2bf(a0.w);
            p.u[4]=f2bf(a1.x); p.u[5]=f2bf(a1.y); p.u[6]=f2bf(a1.z); p.u[7]=f2bf(a1.w);
            *(int4*)&As[sr * 32 + sc] = p.v;
        }
        {
            union { u16 u[8]; int4 v; } p;
            p.u[0]=f2bf(a2.x); p.u[1]=f2bf(a2.y); p.u[2]=f2bf(a2.z); p.u[3]=f2bf(a2.w);
            p.u[4]=f2bf(a3.x); p.u[5]=f2bf(a3.y); p.u[6]=f2bf(a3.z); p.u[7]=f2bf(a3.w);
            *(int4*)&As[(sr + 64) * 32 + sc] = p.v;
        }
        *(int4*)&Bs[sr * 32 + sc] = b0;
        *(int4*)&Bs[(sr + 64) * 32 + sc] = b1;
        __syncthreads();

        short8 af[4], bfr[4];
        #pragma unroll
        for (int i = 0; i < 4; ++i)
            af[i] = *(const short8*)&As[(wm + i * 16 + lm) * 32 + lq * 8];
        #pragma unroll
        for (int i = 0; i < 4; ++i)
            bfr[i] = *(const short8*)&Bs[(wn + i * 16 + lm) * 32 + lq * 8];
        #pragma unroll
        for (int i = 0; i < 4; ++i)
            #pragma unroll
            for (int j = 0; j < 4; ++j)
                acc[i][j] = __builtin_amdgcn_mfma_f32_16x16x32_bf16(
                    af[i], bfr[j], acc[i][j], 0, 0, 0);
    }

    // epilogue: n<384 -> K (scatter u16), n>=384 -> V^T (packed 8B)
    #pragma unroll
    for (int i = 0; i < 4; ++i) {
        const int mrow = m0 + wm + i * 16 + lq * 4;   // global emb row = b*1024+s
        const int bb = mrow >> 10, s = mrow & 1023;
        #pragma unroll
        for (int j = 0; j < 4; ++j) {
            const int n = n0 + wn + j * 16 + lm;
            if (n < HDH) {
                const int hh = n / 48, dd = n - hh * 48;
                u16* kp = &Kp[(((size_t)(bb * N_HEAD + hh)) * S_LEN + s) * 64 + dd];
                kp[0]   = f2bf(acc[i][j][0]);
                kp[64]  = f2bf(acc[i][j][1]);
                kp[128] = f2bf(acc[i][j][2]);
                kp[192] = f2bf(acc[i][j][3]);
            } else {
                const int nv = n - HDH;
                const int hh = nv / 48, dd = nv - hh * 48;
                ushort4v pk;
                pk[0] = f2bf(acc[i][j][0]); pk[1] = f2bf(acc[i][j][1]);
                pk[2] = f2bf(acc[i][j][2]); pk[3] = f2bf(acc[i][j][3]);
                *(ushort4v*)&VTt[(((size_t)(bb * N_HEAD + hh)) * 48 + dd) * S_LEN + s] = pk;
            }
        }
    }
}

// ---------------------------------------------------------------------------
// fused Q|gate projection: [2048 x 768] = yb[2048 x 256] @ WT2[768 x 256]^T
// bf16 MFMA, same tile structure as kv_gemm, all-bf16 staging.
// Epilogue: n<384 -> Qb[h][m][64] (bf16, scaled); n>=384 -> gate fp32 sigmoid.
// ---------------------------------------------------------------------------
__global__ __launch_bounds__(256)
void qg_gemm(const u16* __restrict__ Ab, const u16* __restrict__ WT2,
             const float* __restrict__ bg, u16* __restrict__ Qb,
             float* __restrict__ gate) {
    __shared__ __align__(16) u16 As[128 * 32];
    __shared__ __align__(16) u16 Bs[128 * 32];
    const int tid = threadIdx.x;
    const int lane = tid & 63, wave = tid >> 6;
    const int wm = (wave >> 1) * 64, wn = (wave & 1) * 64;
    const int m0 = blockIdx.y * 128, n0 = blockIdx.x * 128;
    const int lm = lane & 15, lq = lane >> 4;

    floatx4 acc[4][4] = {};
    const int sr = tid >> 2;
    const int sc = (tid & 3) * 8;

    for (int k0 = 0; k0 < D; k0 += 32) {
        const int4 a0 = *(const int4*)&Ab[(size_t)(m0 + sr) * D + k0 + sc];
        const int4 a1 = *(const int4*)&Ab[(size_t)(m0 + sr + 64) * D + k0 + sc];
        const int4 b0 = *(const int4*)&WT2[(size_t)(n0 + sr) * D + k0 + sc];
        const int4 b1 = *(const int4*)&WT2[(size_t)(n0 + sr + 64) * D + k0 + sc];
        __syncthreads();
        *(int4*)&As[sr * 32 + sc] = a0;
        *(int4*)&As[(sr + 64) * 32 + sc] = a1;
        *(int4*)&Bs[sr * 32 + sc] = b0;
        *(int4*)&Bs[(sr + 64) * 32 + sc] = b1;
        __syncthreads();

        short8 af[4], bfr[4];
        #pragma unroll
        for (int i = 0; i < 4; ++i)
            af[i] = *(const short8*)&As[(wm + i * 16 + lm) * 32 + lq * 8];
        #pragma unroll
        for (int i = 0; i < 4; ++i)
            bfr[i] = *(const short8*)&Bs[(wn + i * 16 + lm) * 32 + lq * 8];
        #pragma unroll
        for (int i = 0; i < 4; ++i)
            #pragma unroll
            for (int j = 0; j < 4; ++j)
                acc[i][j] = __builtin_amdgcn_mfma_f32_16x16x32_bf16(
                    af[i], bfr[j], acc[i][j], 0, 0, 0);
    }

    #pragma unroll
    for (int i = 0; i < 4; ++i) {
        const int mb = m0 + wm + i * 16 + lq * 4;
        #pragma unroll
        for (int j = 0; j < 4; ++j) {
            const int n = n0 + wn + j * 16 + lm;
            #pragma unroll
            for (int r = 0; r < 4; ++r) {
                const int m = mb + r;
                const float v = acc[i][j][r];
                if (n < HDH) {
                    const int hh = n / 48, dd = n - hh * 48;
                    Qb[((size_t)hh * QROWS + m) * 64 + dd] = f2bf(v * INV_SCALE);
                } else {
                    const int ng = n - HDH;
                    gate[(size_t)m * HDH + ng] = 1.f / (1.f + __expf(-(v + bg[ng])));
                }
            }
        }
    }
}

// ---------------------------------------------------------------------------
// fp32 GEMM 64x64 tile — used only for the back-projection (bias + residual)
// ---------------------------------------------------------------------------
__global__ __launch_bounds__(256)
void gemm64(const float* __restrict__ A, const float* __restrict__ B,
            float* __restrict__ C, int M, int N, int K,
            const float* __restrict__ bias, const float* __restrict__ resid) {
    __shared__ float Asm[16][68];
    __shared__ float Bsm[16][68];
    const int tid = threadIdx.x;
    const int tx = tid & 15, ty = tid >> 4;
    const int m0 = blockIdx.y * 64, n0 = blockIdx.x * 64;
    float c[4][4] = {};

    const int ka = tid & 15, ma = tid >> 4;
    const int nb = tid & 63, kb = tid >> 6;

    for (int k0 = 0; k0 < K; k0 += 16) {
        #pragma unroll
        for (int i = 0; i < 4; ++i)
            Asm[ka][ma + 16 * i] = A[(size_t)(m0 + ma + 16 * i) * K + k0 + ka];
        #pragma unroll
        for (int i = 0; i < 4; ++i)
            Bsm[kb + 4 * i][nb] = B[(size_t)(k0 + kb + 4 * i) * N + n0 + nb];
        __syncthreads();
        #pragma unroll
        for (int kk = 0; kk < 16; ++kk) {
            float4 av = *(const float4*)&Asm[kk][ty * 4];
            float4 bv = *(const float4*)&Bsm[kk][tx * 4];
            float a[4] = {av.x, av.y, av.z, av.w};
            float bb[4] = {bv.x, bv.y, bv.z, bv.w};
            #pragma unroll
            for (int i = 0; i < 4; ++i)
                #pragma unroll
                for (int j = 0; j < 4; ++j)
                    c[i][j] += a[i] * bb[j];
        }
        __syncthreads();
    }

    #pragma unroll
    for (int i = 0; i < 4; ++i) {
        int m = m0 + ty * 4 + i;
        #pragma unroll
        for (int j = 0; j < 4; ++j) {
            int n = n0 + tx * 4 + j;
            float v = c[i][j] + bias[n] + resid[(size_t)m * N + n];
            C[(size_t)m * N + n] = v;
        }
    }
}

// ---------------------------------------------------------------------------
// MFMA flash attention, register-prefetched.
// Grid (b, h, tile): b fastest -> XCD round-robin keeps one graph per XCD L2.
// Block = 16-node tile; 4 waves partition S (256 each); no LDS in main loop.
// ---------------------------------------------------------------------------
__global__ __launch_bounds__(256)
void attn_mfma(const u16* __restrict__ Qb, const u16* __restrict__ Kp,
               const u16* __restrict__ VTt, const int* __restrict__ mask,
               const float* __restrict__ gate, const int* __restrict__ ranges,
               float* __restrict__ gfeat) {
    const int b = blockIdx.x, h = blockIdx.y, tile = blockIdx.z;
    const int nstart = ranges[b], nend = ranges[b + 1];
    const int n0 = nstart + tile * 16;
    if (n0 >= nend) return;
    const int NT = min(16, nend - n0);

    const int tid = threadIdx.x;
    const int wave = tid >> 6, lane = tid & 63;
    const int lm = lane & 15, lq = lane >> 4;
    const int bh = b * N_HEAD + h;

    const u16* qrow = &Qb[((size_t)h * QROWS + n0 + lm) * 64];
    const short8 qf0 = *(const short8*)&qrow[lq * 8];
    const short8 qf1 = *(const short8*)&qrow[32 + lq * 8];

    const u16* kbase = &Kp[(size_t)bh * S_LEN * 64];
    const u16* vbase = &VTt[(size_t)bh * 48 * S_LEN];
    const int* mrow = &mask[b * S_LEN];

    float m_i = -1e30f, l_i = 0.f;
    floatx4 acc0 = {}, acc1 = {}, acc2 = {};

    const int sbase = wave * 256;
    // prefetch t=0
    const u16* kr0 = &kbase[(size_t)(sbase + lm) * 64];
    short8 nkf0 = *(const short8*)&kr0[lq * 8];
    short8 nkf1 = *(const short8*)&kr0[32 + lq * 8];
    int4 nmv = *(const int4*)&mrow[sbase + lq * 4];
    short4v nvf0 = *(const short4v*)&vbase[(size_t)lm * S_LEN + sbase + lq * 4];
    short4v nvf1 = *(const short4v*)&vbase[(size_t)(16 + lm) * S_LEN + sbase + lq * 4];
    short4v nvf2 = *(const short4v*)&vbase[(size_t)(32 + lm) * S_LEN + sbase + lq * 4];

    for (int t = 0; t < 16; ++t) {
        const short8 kf0 = nkf0, kf1 = nkf1;
        const int4 mv = nmv;
        const short4v vf0 = nvf0, vf1 = nvf1, vf2 = nvf2;
        if (t < 15) {
            const int s1 = sbase + (t + 1) * 16;
            const u16* kr = &kbase[(size_t)(s1 + lm) * 64];
            nkf0 = *(const short8*)&kr[lq * 8];
            nkf1 = *(const short8*)&kr[32 + lq * 8];
            nmv = *(const int4*)&mrow[s1 + lq * 4];
            nvf0 = *(const short4v*)&vbase[(size_t)lm * S_LEN + s1 + lq * 4];
            nvf1 = *(const short4v*)&vbase[(size_t)(16 + lm) * S_LEN + s1 + lq * 4];
            nvf2 = *(const short4v*)&vbase[(size_t)(32 + lm) * S_LEN + s1 + lq * 4];
        }

        floatx4 st = {};
        st = __builtin_amdgcn_mfma_f32_16x16x32_bf16(kf0, qf0, st, 0, 0, 0);
        st = __builtin_amdgcn_mfma_f32_16x16x32_bf16(kf1, qf1, st, 0, 0, 0);

        const float sv0 = mv.x > 0 ? st[0] : -1e30f;
        const float sv1 = mv.y > 0 ? st[1] : -1e30f;
        const float sv2 = mv.z > 0 ? st[2] : -1e30f;
        const float sv3 = mv.w > 0 ? st[3] : -1e30f;
        float tmax = fmaxf(fmaxf(sv0, sv1), fmaxf(sv2, sv3));
        tmax = fmaxf(tmax, __shfl_xor(tmax, 16));
        tmax = fmaxf(tmax, __shfl_xor(tmax, 32));
        const float m_new = fmaxf(m_i, tmax);
        const float alpha = __expf(m_i - m_new);
        const float p0 = mv.x > 0 ? __expf(st[0] - m_new) : 0.f;
        const float p1 = mv.y > 0 ? __expf(st[1] - m_new) : 0.f;
        const float p2 = mv.z > 0 ? __expf(st[2] - m_new) : 0.f;
        const float p3 = mv.w > 0 ? __expf(st[3] - m_new) : 0.f;
        float ls = p0 + p1 + p2 + p3;
        ls += __shfl_xor(ls, 16);
        ls += __shfl_xor(ls, 32);
        m_i = m_new;
        l_i = l_i * alpha + ls;
        acc0 *= alpha; acc1 *= alpha; acc2 *= alpha;

        short4v pf;
        pf[0] = (short)f2bf(p0); pf[1] = (short)f2bf(p1);
        pf[2] = (short)f2bf(p2); pf[3] = (short)f2bf(p3);

        acc0 = __builtin_amdgcn_mfma_f32_16x16x16bf16_1k(vf0, pf, acc0, 0, 0, 0);
        acc1 = __builtin_amdgcn_mfma_f32_16x16x16bf16_1k(vf1, pf, acc1, 0, 0, 0);
        acc2 = __builtin_amdgcn_mfma_f32_16x16x16bf16_1k(vf2, pf, acc2, 0, 0, 0);
    }

    // cross-wave combine
    __shared__ float sm[4][64], sl[4][64];
    __shared__ float sacc[4][3][4][64];
    sm[wave][lane] = m_i;
    sl[wave][lane] = l_i;
    #pragma unroll
    for (int r = 0; r < 4; ++r) {
        sacc[wave][0][r][lane] = acc0[r];
        sacc[wave][1][r][lane] = acc1[r];
        sacc[wave][2][r][lane] = acc2[r];
    }
    __syncthreads();
    if (wave < 3 && lm < NT) {
        const int dt = wave;
        const float M = fmaxf(fmaxf(sm[0][lane], sm[1][lane]),
                              fmaxf(sm[2][lane], sm[3][lane]));
        const float f0 = __expf(sm[0][lane] - M);
        const float f1 = __expf(sm[1][lane] - M);
        const float f2 = __expf(sm[2][lane] - M);
        const float f3 = __expf(sm[3][lane] - M);
        const float L = sl[0][lane] * f0 + sl[1][lane] * f1 +
                        sl[2][lane] * f2 + sl[3][lane] * f3;
        const float invl = 1.f / (L + 1e-9f);
        const size_t o = (size_t)(n0 + lm) * HDH + h * 48 + dt * 16 + lq * 4;
        const float4 g4 = *(const float4*)&gate[o];
        float4 ov;
        ov.x = (sacc[0][dt][0][lane] * f0 + sacc[1][dt][0][lane] * f1 +
                sacc[2][dt][0][lane] * f2 + sacc[3][dt][0][lane] * f3) * invl * g4.x;
        ov.y = (sacc[0][dt][1][lane] * f0 + sacc[1][dt][1][lane] * f1 +
                sacc[2][dt][1][lane] * f2 + sacc[3][dt][1][lane] * f3) * invl * g4.y;
        ov.z = (sacc[0][dt][2][lane] * f0 + sacc[1][dt][2][lane] * f1 +
                sacc[2][dt][2][lane] * f2 + sacc[3][dt][2][lane] * f3) * invl * g4.z;
        ov.w = (sacc[0][dt][3][lane] * f0 + sacc[1][dt][3][lane] * f1 +
                sacc[2][dt][3][lane] * f2 + sacc[3][dt][3][lane] * f3) * invl * g4.w;
        *(float4*)&gfeat[o] = ov;
    }
}

// ---------------------------------------------------------------------------
extern "C" void kernel_launch(void* const* d_in, const int* in_sizes, int n_in,
                              void* d_out, int out_size, void* d_ws, size_t ws_size,
                              hipStream_t stream) {
    const float* node  = (const float*)d_in[0];
    const float* emb   = (const float*)d_in[1];
    const int*   mask  = (const int*)d_in[2];
    const int*   batch = (const int*)d_in[3];
    const float* ln_g  = (const float*)d_in[4];
    const float* ln_b  = (const float*)d_in[5];
    const float* Wq    = (const float*)d_in[6];
    const float* Wk    = (const float*)d_in[7];
    const float* Wv    = (const float*)d_in[8];
    const float* Wg    = (const float*)d_in[9];
    const float* bg    = (const float*)d_in[10];
    const float* Wback = (const float*)d_in[11];
    const float* bback = (const float*)d_in[12];
    float* out = (float*)d_out;

    float* ws    = (float*)d_ws;
    float* gate  = ws;                                     // 2048*384 f32
    float* gfeat = gate + (size_t)N_NODE * HDH;            // 2048*384 f32
    u16*   yb    = (u16*)(gfeat + (size_t)N_NODE * HDH);   // 2048*256 u16
    u16*   WT    = yb + (size_t)N_NODE * D;                // 768*1280 u16
    u16*   WT2   = WT + (size_t)KVN * D_SEQ;               // 768*256 u16
    u16*   Qb    = WT2 + (size_t)QGN * D;                  // 8*2064*64 u16
    u16*   Kp    = Qb + (size_t)N_HEAD * QROWS * 64;       // 64*1024*64 u16
    u16*   VTt   = Kp + (size_t)B_GRAPH * N_HEAD * S_LEN * 64;  // 64*48*1024 u16
    int*   ranges = (int*)(VTt + (size_t)B_GRAPH * N_HEAD * 48 * S_LEN);

    ranges_kernel<<<1, 64, 0, stream>>>(batch, ranges);
    ln_kernel<<<N_NODE, 256, 0, stream>>>(node, ln_g, ln_b, yb);
    wt_kernel<<<dim3(D_SEQ / 256, KVN), 256, 0, stream>>>(Wk, Wv, WT);
    wt2_kernel<<<QGN, 256, 0, stream>>>(Wq, Wg, WT2);
    // zero pads (Qb rows/cols, Kp d=48..63)
    (void)hipMemsetAsync(Qb, 0, (size_t)N_HEAD * QROWS * 64 * 2, stream);
    (void)hipMemsetAsync(Kp, 0, (size_t)B_GRAPH * N_HEAD * S_LEN * 64 * 2, stream);
    // fused K|V projection -> bf16 attention layouts
    kv_gemm<<<dim3(KVN / 128, (B_GRAPH * S_LEN) / 128), 256, 0, stream>>>(
        emb, WT, Kp, VTt);
    // fused Q|gate projection
    qg_gemm<<<dim3(QGN / 128, N_NODE / 128), 256, 0, stream>>>(
        yb, WT2, bg, Qb, gate);
    // attention (b fastest -> XCD locality)
    attn_mfma<<<dim3(B_GRAPH, N_HEAD, 32), 256, 0, stream>>>(
        Qb, Kp, VTt, mask, gate, ranges, gfeat);
    // out = node + gfeat @ Wback + bback
    gemm64<<<dim3(D / 64, N_NODE / 64), 256, 0, stream>>>(
        gfeat, Wback, out, N_NODE, D, HDH, bback, node);
}

// Round 6
// 265.718 us; speedup vs baseline: 2.8298x; 1.0240x over previous
//
#include <hip/hip_runtime.h>
#include <hip/hip_bf16.h>
#include <math.h>

#define D 256
#define D_SEQ 1280
#define D_HEAD 48
#define N_HEAD 8
#define HDH 384        // N_HEAD * D_HEAD
#define N_NODE 2048
#define B_GRAPH 8
#define S_LEN 1024
#define LN_EPS 1e-5f
#define INV_SCALE 0.14433756729740643f   // 1/sqrt(48)
#define KVN 768        // fused K|V gemm output width
#define QGN 768        // fused Q|gate gemm output width
#define QROWS (N_NODE + 16)              // padded Q rows per head

typedef unsigned short u16;
typedef __attribute__((ext_vector_type(8))) short short8;
typedef __attribute__((ext_vector_type(4))) short short4v;
typedef __attribute__((ext_vector_type(4))) unsigned short ushort4v;
typedef __attribute__((ext_vector_type(4))) float floatx4;

__device__ __forceinline__ u16 f2bf(float f) {
    unsigned int x = __float_as_uint(f);
    x += 0x7fff + ((x >> 16) & 1);      // RNE to bf16
    return (u16)(x >> 16);
}

// async 16B-per-lane global->LDS DMA. LDS dest: ldsbase + lane*16B (wave-uniform
// base); global src: per-lane pointer.
__device__ __forceinline__ void load_lds16(const u16* g, u16* lds) {
    __builtin_amdgcn_global_load_lds(
        (const __attribute__((address_space(1))) unsigned int*)g,
        (__attribute__((address_space(3))) unsigned int*)lds, 16, 0, 0);
}

// ---------------------------------------------------------------------------
__global__ void ranges_kernel(const int* __restrict__ batch, int* __restrict__ ranges) {
    int t = threadIdx.x;
    if (t <= B_GRAPH) {
        int lo = 0, hi = N_NODE;
        while (lo < hi) {
            int mid = (lo + hi) >> 1;
            if (batch[mid] < t) lo = mid + 1; else hi = mid;
        }
        ranges[t] = lo;
    }
}

// ---------------------------------------------------------------------------
// emb fp32 -> bf16 (feeds kv_gemm). 8 elems/thread.
// ---------------------------------------------------------------------------
__global__ __launch_bounds__(256)
void tobf16_kernel(const float* __restrict__ in, u16* __restrict__ out) {
    const size_t i = ((size_t)blockIdx.x * 256 + threadIdx.x) * 8;
    const float4 a = *(const float4*)&in[i];
    const float4 b = *(const float4*)&in[i + 4];
    union { u16 u[8]; int4 v; } p;
    p.u[0]=f2bf(a.x); p.u[1]=f2bf(a.y); p.u[2]=f2bf(a.z); p.u[3]=f2bf(a.w);
    p.u[4]=f2bf(b.x); p.u[5]=f2bf(b.y); p.u[6]=f2bf(b.z); p.u[7]=f2bf(b.w);
    *(int4*)&out[i] = p.v;
}

// ---------------------------------------------------------------------------
// layernorm -> bf16 output (consumed by qg_gemm)
// ---------------------------------------------------------------------------
__global__ __launch_bounds__(256)
void ln_kernel(const float* __restrict__ node, const float* __restrict__ g,
               const float* __restrict__ b, u16* __restrict__ yb) {
    int n = blockIdx.x, t = threadIdx.x;
    float x = node[n * D + t];
    float s = x, sq = x * x;
    #pragma unroll
    for (int o = 32; o > 0; o >>= 1) {
        s  += __shfl_down(s, o);
        sq += __shfl_down(sq, o);
    }
    __shared__ float ss[4], sqs[4];
    if ((t & 63) == 0) { ss[t >> 6] = s; sqs[t >> 6] = sq; }
    __syncthreads();
    float S  = ss[0] + ss[1] + ss[2] + ss[3];
    float SQ = sqs[0] + sqs[1] + sqs[2] + sqs[3];
    float mu  = S * (1.f / D);
    float var = SQ * (1.f / D) - mu * mu;
    float inv = rsqrtf(var + LN_EPS);
    yb[n * D + t] = f2bf((x - mu) * inv * g[t] + b[t]);
}

// ---------------------------------------------------------------------------
// LDS-tiled transpose+convert: W[K][Ncols] fp32 -> WTo[Ncols][K] bf16.
// Both global accesses coalesced. Block 256 = 32x8, tile 32x32.
// ---------------------------------------------------------------------------
__global__ __launch_bounds__(256)
void wtr_kernel(const float* __restrict__ W, u16* __restrict__ WTo,
                int K, int Ncols) {
    __shared__ float tile[32][33];
    const int k0 = blockIdx.x * 32, n0 = blockIdx.y * 32;
    const int tx = threadIdx.x & 31, ty = threadIdx.x >> 5;
    #pragma unroll
    for (int i = 0; i < 32; i += 8)
        tile[ty + i][tx] = W[(size_t)(k0 + ty + i) * Ncols + n0 + tx];
    __syncthreads();
    #pragma unroll
    for (int i = 0; i < 32; i += 8)
        WTo[(size_t)(n0 + ty + i) * K + k0 + tx] = f2bf(tile[tx][ty + i]);
}

// ---------------------------------------------------------------------------
// fused K|V projection, m97-style: all-bf16, global_load_lds(16B) staging,
// LDS layout [kb][row][8] (kb = k/8) -> conflict-free ds_read_b128 frags.
// Grid: 384 linear, swizzled so the 6 N-blocks of one M-block share an XCD.
// Epilogue: K -> Kp[b][h][s][64] (d-pad zeroed), V -> VT[b][h][d][s].
// ---------------------------------------------------------------------------
__global__ __launch_bounds__(256)
void kv_gemm(const u16* __restrict__ A, const u16* __restrict__ WT,
             u16* __restrict__ Kp, u16* __restrict__ VTt) {
    __shared__ __align__(16) u16 As[128 * 32];   // [kb][row][8]
    __shared__ __align__(16) u16 Bs[128 * 32];
    const int tid = threadIdx.x;
    const int lane = tid & 63, wave = tid >> 6;
    const int glin = blockIdx.x;
    const int xcd = glin & 7, rest = glin >> 3;
    const int m0 = (xcd + 8 * (rest / 6)) * 128;   // 64 M-blocks
    const int n0 = (rest % 6) * 128;               // 6 N-blocks
    const int wm = (wave >> 1) * 64, wn = (wave & 1) * 64;
    const int lm = lane & 15, lq = lane >> 4;

    floatx4 acc[4][4] = {};

    // staging: wave w stages kb-chunk w. LDS u16 idx = w*1024 + row*8 (+512 for
    // rows 64..127); global lane l -> row l, k-offset w*8.
    u16* asb = &As[wave * 1024];
    u16* bsb = &Bs[wave * 1024];
    const u16* ag = &A[(size_t)(m0 + lane) * D_SEQ + wave * 8];
    const u16* bg = &WT[(size_t)(n0 + lane) * D_SEQ + wave * 8];

    for (int k0 = 0; k0 < D_SEQ; k0 += 32) {
        __syncthreads();                       // prev tile's frag reads done
        load_lds16(ag + k0, asb);
        load_lds16(ag + (size_t)64 * D_SEQ + k0, asb + 512);
        load_lds16(bg + k0, bsb);
        load_lds16(bg + (size_t)64 * D_SEQ + k0, bsb + 512);
        __syncthreads();                       // vmcnt drain: tile visible

        short8 af[4], bfr[4];
        #pragma unroll
        for (int i = 0; i < 4; ++i)
            af[i] = *(const short8*)&As[lq * 1024 + (wm + i * 16 + lm) * 8];
        #pragma unroll
        for (int i = 0; i < 4; ++i)
            bfr[i] = *(const short8*)&Bs[lq * 1024 + (wn + i * 16 + lm) * 8];
        #pragma unroll
        for (int i = 0; i < 4; ++i)
            #pragma unroll
            for (int j = 0; j < 4; ++j)
                acc[i][j] = __builtin_amdgcn_mfma_f32_16x16x32_bf16(
                    af[i], bfr[j], acc[i][j], 0, 0, 0);
    }

    // epilogue: n<384 -> K (scatter u16), n>=384 -> V^T (packed 8B)
    #pragma unroll
    for (int i = 0; i < 4; ++i) {
        const int mrow = m0 + wm + i * 16 + lq * 4;   // emb row = b*1024+s
        const int bb = mrow >> 10, s = mrow & 1023;
        #pragma unroll
        for (int j = 0; j < 4; ++j) {
            const int n = n0 + wn + j * 16 + lm;
            if (n < HDH) {
                const int hh = n / 48, dd = n - hh * 48;
                u16* kp = &Kp[(((size_t)(bb * N_HEAD + hh)) * S_LEN + s) * 64 + dd];
                kp[0]   = f2bf(acc[i][j][0]);
                kp[64]  = f2bf(acc[i][j][1]);
                kp[128] = f2bf(acc[i][j][2]);
                kp[192] = f2bf(acc[i][j][3]);
            } else {
                const int nv = n - HDH;
                const int hh = nv / 48, dd = nv - hh * 48;
                ushort4v pk;
                pk[0] = f2bf(acc[i][j][0]); pk[1] = f2bf(acc[i][j][1]);
                pk[2] = f2bf(acc[i][j][2]); pk[3] = f2bf(acc[i][j][3]);
                *(ushort4v*)&VTt[(((size_t)(bb * N_HEAD + hh)) * 48 + dd) * S_LEN + s] = pk;
            }
        }
    }
}

// ---------------------------------------------------------------------------
// fused Q|gate projection (round-5 structure, K=256)
// ---------------------------------------------------------------------------
__global__ __launch_bounds__(256)
void qg_gemm(const u16* __restrict__ Ab, const u16* __restrict__ WT2,
             const float* __restrict__ bg, u16* __restrict__ Qb,
             float* __restrict__ gate) {
    __shared__ __align__(16) u16 As[128 * 32];
    __shared__ __align__(16) u16 Bs[128 * 32];
    const int tid = threadIdx.x;
    const int lane = tid & 63, wave = tid >> 6;
    const int wm = (wave >> 1) * 64, wn = (wave & 1) * 64;
    const int m0 = blockIdx.y * 128, n0 = blockIdx.x * 128;
    const int lm = lane & 15, lq = lane >> 4;

    floatx4 acc[4][4] = {};
    const int sr = tid >> 2;
    const int sc = (tid & 3) * 8;

    for (int k0 = 0; k0 < D; k0 += 32) {
        const int4 a0 = *(const int4*)&Ab[(size_t)(m0 + sr) * D + k0 + sc];
        const int4 a1 = *(const int4*)&Ab[(size_t)(m0 + sr + 64) * D + k0 + sc];
        const int4 b0 = *(const int4*)&WT2[(size_t)(n0 + sr) * D + k0 + sc];
        const int4 b1 = *(const int4*)&WT2[(size_t)(n0 + sr + 64) * D + k0 + sc];
        __syncthreads();
        *(int4*)&As[sr * 32 + sc] = a0;
        *(int4*)&As[(sr + 64) * 32 + sc] = a1;
        *(int4*)&Bs[sr * 32 + sc] = b0;
        *(int4*)&Bs[(sr + 64) * 32 + sc] = b1;
        __syncthreads();

        short8 af[4], bfr[4];
        #pragma unroll
        for (int i = 0; i < 4; ++i)
            af[i] = *(const short8*)&As[(wm + i * 16 + lm) * 32 + lq * 8];
        #pragma unroll
        for (int i = 0; i < 4; ++i)
            bfr[i] = *(const short8*)&Bs[(wn + i * 16 + lm) * 32 + lq * 8];
        #pragma unroll
        for (int i = 0; i < 4; ++i)
            #pragma unroll
            for (int j = 0; j < 4; ++j)
                acc[i][j] = __builtin_amdgcn_mfma_f32_16x16x32_bf16(
                    af[i], bfr[j], acc[i][j], 0, 0, 0);
    }

    #pragma unroll
    for (int i = 0; i < 4; ++i) {
        const int mb = m0 + wm + i * 16 + lq * 4;
        #pragma unroll
        for (int j = 0; j < 4; ++j) {
            const int n = n0 + wn + j * 16 + lm;
            #pragma unroll
            for (int r = 0; r < 4; ++r) {
                const int m = mb + r;
                const float v = acc[i][j][r];
                if (n < HDH) {
                    const int hh = n / 48, dd = n - hh * 48;
                    Qb[((size_t)hh * QROWS + m) * 64 + dd] = f2bf(v * INV_SCALE);
                } else {
                    const int ng = n - HDH;
                    gate[(size_t)m * HDH + ng] = 1.f / (1.f + __expf(-(v + bg[ng])));
                }
            }
        }
    }
}

// ---------------------------------------------------------------------------
// fp32 GEMM 64x64 tile — back-projection only (bias + residual)
// ---------------------------------------------------------------------------
__global__ __launch_bounds__(256)
void gemm64(const float* __restrict__ A, const float* __restrict__ B,
            float* __restrict__ C, int M, int N, int K,
            const float* __restrict__ bias, const float* __restrict__ resid) {
    __shared__ float Asm[16][68];
    __shared__ float Bsm[16][68];
    const int tid = threadIdx.x;
    const int tx = tid & 15, ty = tid >> 4;
    const int m0 = blockIdx.y * 64, n0 = blockIdx.x * 64;
    float c[4][4] = {};

    const int ka = tid & 15, ma = tid >> 4;
    const int nb = tid & 63, kb = tid >> 6;

    for (int k0 = 0; k0 < K; k0 += 16) {
        #pragma unroll
        for (int i = 0; i < 4; ++i)
            Asm[ka][ma + 16 * i] = A[(size_t)(m0 + ma + 16 * i) * K + k0 + ka];
        #pragma unroll
        for (int i = 0; i < 4; ++i)
            Bsm[kb + 4 * i][nb] = B[(size_t)(k0 + kb + 4 * i) * N + n0 + nb];
        __syncthreads();
        #pragma unroll
        for (int kk = 0; kk < 16; ++kk) {
            float4 av = *(const float4*)&Asm[kk][ty * 4];
            float4 bv = *(const float4*)&Bsm[kk][tx * 4];
            float a[4] = {av.x, av.y, av.z, av.w};
            float bb[4] = {bv.x, bv.y, bv.z, bv.w};
            #pragma unroll
            for (int i = 0; i < 4; ++i)
                #pragma unroll
                for (int j = 0; j < 4; ++j)
                    c[i][j] += a[i] * bb[j];
        }
        __syncthreads();
    }

    #pragma unroll
    for (int i = 0; i < 4; ++i) {
        int m = m0 + ty * 4 + i;
        #pragma unroll
        for (int j = 0; j < 4; ++j) {
            int n = n0 + tx * 4 + j;
            C[(size_t)m * N + n] = c[i][j] + bias[n] + resid[(size_t)m * N + n];
        }
    }
}

// ---------------------------------------------------------------------------
// MFMA flash attention, register-prefetched (round-5, unchanged).
// ---------------------------------------------------------------------------
__global__ __launch_bounds__(256)
void attn_mfma(const u16* __restrict__ Qb, const u16* __restrict__ Kp,
               const u16* __restrict__ VTt, const int* __restrict__ mask,
               const float* __restrict__ gate, const int* __restrict__ ranges,
               float* __restrict__ gfeat) {
    const int b = blockIdx.x, h = blockIdx.y, tile = blockIdx.z;
    const int nstart = ranges[b], nend = ranges[b + 1];
    const int n0 = nstart + tile * 16;
    if (n0 >= nend) return;
    const int NT = min(16, nend - n0);

    const int tid = threadIdx.x;
    const int wave = tid >> 6, lane = tid & 63;
    const int lm = lane & 15, lq = lane >> 4;
    const int bh = b * N_HEAD + h;

    const u16* qrow = &Qb[((size_t)h * QROWS + n0 + lm) * 64];
    const short8 qf0 = *(const short8*)&qrow[lq * 8];
    const short8 qf1 = *(const short8*)&qrow[32 + lq * 8];

    const u16* kbase = &Kp[(size_t)bh * S_LEN * 64];
    const u16* vbase = &VTt[(size_t)bh * 48 * S_LEN];
    const int* mrow = &mask[b * S_LEN];

    float m_i = -1e30f, l_i = 0.f;
    floatx4 acc0 = {}, acc1 = {}, acc2 = {};

    const int sbase = wave * 256;
    const u16* kr0 = &kbase[(size_t)(sbase + lm) * 64];
    short8 nkf0 = *(const short8*)&kr0[lq * 8];
    short8 nkf1 = *(const short8*)&kr0[32 + lq * 8];
    int4 nmv = *(const int4*)&mrow[sbase + lq * 4];
    short4v nvf0 = *(const short4v*)&vbase[(size_t)lm * S_LEN + sbase + lq * 4];
    short4v nvf1 = *(const short4v*)&vbase[(size_t)(16 + lm) * S_LEN + sbase + lq * 4];
    short4v nvf2 = *(const short4v*)&vbase[(size_t)(32 + lm) * S_LEN + sbase + lq * 4];

    for (int t = 0; t < 16; ++t) {
        const short8 kf0 = nkf0, kf1 = nkf1;
        const int4 mv = nmv;
        const short4v vf0 = nvf0, vf1 = nvf1, vf2 = nvf2;
        if (t < 15) {
            const int s1 = sbase + (t + 1) * 16;
            const u16* kr = &kbase[(size_t)(s1 + lm) * 64];
            nkf0 = *(const short8*)&kr[lq * 8];
            nkf1 = *(const short8*)&kr[32 + lq * 8];
            nmv = *(const int4*)&mrow[s1 + lq * 4];
            nvf0 = *(const short4v*)&vbase[(size_t)lm * S_LEN + s1 + lq * 4];
            nvf1 = *(const short4v*)&vbase[(size_t)(16 + lm) * S_LEN + s1 + lq * 4];
            nvf2 = *(const short4v*)&vbase[(size_t)(32 + lm) * S_LEN + s1 + lq * 4];
        }

        floatx4 st = {};
        st = __builtin_amdgcn_mfma_f32_16x16x32_bf16(kf0, qf0, st, 0, 0, 0);
        st = __builtin_amdgcn_mfma_f32_16x16x32_bf16(kf1, qf1, st, 0, 0, 0);

        const float sv0 = mv.x > 0 ? st[0] : -1e30f;
        const float sv1 = mv.y > 0 ? st[1] : -1e30f;
        const float sv2 = mv.z > 0 ? st[2] : -1e30f;
        const float sv3 = mv.w > 0 ? st[3] : -1e30f;
        float tmax = fmaxf(fmaxf(sv0, sv1), fmaxf(sv2, sv3));
        tmax = fmaxf(tmax, __shfl_xor(tmax, 16));
        tmax = fmaxf(tmax, __shfl_xor(tmax, 32));
        const float m_new = fmaxf(m_i, tmax);
        const float alpha = __expf(m_i - m_new);
        const float p0 = mv.x > 0 ? __expf(st[0] - m_new) : 0.f;
        const float p1 = mv.y > 0 ? __expf(st[1] - m_new) : 0.f;
        const float p2 = mv.z > 0 ? __expf(st[2] - m_new) : 0.f;
        const float p3 = mv.w > 0 ? __expf(st[3] - m_new) : 0.f;
        float ls = p0 + p1 + p2 + p3;
        ls += __shfl_xor(ls, 16);
        ls += __shfl_xor(ls, 32);
        m_i = m_new;
        l_i = l_i * alpha + ls;
        acc0 *= alpha; acc1 *= alpha; acc2 *= alpha;

        short4v pf;
        pf[0] = (short)f2bf(p0); pf[1] = (short)f2bf(p1);
        pf[2] = (short)f2bf(p2); pf[3] = (short)f2bf(p3);

        acc0 = __builtin_amdgcn_mfma_f32_16x16x16bf16_1k(vf0, pf, acc0, 0, 0, 0);
        acc1 = __builtin_amdgcn_mfma_f32_16x16x16bf16_1k(vf1, pf, acc1, 0, 0, 0);
        acc2 = __builtin_amdgcn_mfma_f32_16x16x16bf16_1k(vf2, pf, acc2, 0, 0, 0);
    }

    __shared__ float sm[4][64], sl[4][64];
    __shared__ float sacc[4][3][4][64];
    sm[wave][lane] = m_i;
    sl[wave][lane] = l_i;
    #pragma unroll
    for (int r = 0; r < 4; ++r) {
        sacc[wave][0][r][lane] = acc0[r];
        sacc[wave][1][r][lane] = acc1[r];
        sacc[wave][2][r][lane] = acc2[r];
    }
    __syncthreads();
    if (wave < 3 && lm < NT) {
        const int dt = wave;
        const float M = fmaxf(fmaxf(sm[0][lane], sm[1][lane]),
                              fmaxf(sm[2][lane], sm[3][lane]));
        const float f0 = __expf(sm[0][lane] - M);
        const float f1 = __expf(sm[1][lane] - M);
        const float f2 = __expf(sm[2][lane] - M);
        const float f3 = __expf(sm[3][lane] - M);
        const float L = sl[0][lane] * f0 + sl[1][lane] * f1 +
                        sl[2][lane] * f2 + sl[3][lane] * f3;
        const float invl = 1.f / (L + 1e-9f);
        const size_t o = (size_t)(n0 + lm) * HDH + h * 48 + dt * 16 + lq * 4;
        const float4 g4 = *(const float4*)&gate[o];
        float4 ov;
        ov.x = (sacc[0][dt][0][lane] * f0 + sacc[1][dt][0][lane] * f1 +
                sacc[2][dt][0][lane] * f2 + sacc[3][dt][0][lane] * f3) * invl * g4.x;
        ov.y = (sacc[0][dt][1][lane] * f0 + sacc[1][dt][1][lane] * f1 +
                sacc[2][dt][1][lane] * f2 + sacc[3][dt][1][lane] * f3) * invl * g4.y;
        ov.z = (sacc[0][dt][2][lane] * f0 + sacc[1][dt][2][lane] * f1 +
                sacc[2][dt][2][lane] * f2 + sacc[3][dt][2][lane] * f3) * invl * g4.z;
        ov.w = (sacc[0][dt][3][lane] * f0 + sacc[1][dt][3][lane] * f1 +
                sacc[2][dt][3][lane] * f2 + sacc[3][dt][3][lane] * f3) * invl * g4.w;
        *(float4*)&gfeat[o] = ov;
    }
}

// ---------------------------------------------------------------------------
extern "C" void kernel_launch(void* const* d_in, const int* in_sizes, int n_in,
                              void* d_out, int out_size, void* d_ws, size_t ws_size,
                              hipStream_t stream) {
    const float* node  = (const float*)d_in[0];
    const float* emb   = (const float*)d_in[1];
    const int*   mask  = (const int*)d_in[2];
    const int*   batch = (const int*)d_in[3];
    const float* ln_g  = (const float*)d_in[4];
    const float* ln_b  = (const float*)d_in[5];
    const float* Wq    = (const float*)d_in[6];
    const float* Wk    = (const float*)d_in[7];
    const float* Wv    = (const float*)d_in[8];
    const float* Wg    = (const float*)d_in[9];
    const float* bg    = (const float*)d_in[10];
    const float* Wback = (const float*)d_in[11];
    const float* bback = (const float*)d_in[12];
    float* out = (float*)d_out;

    float* ws    = (float*)d_ws;
    float* gate  = ws;                                     // 2048*384 f32
    float* gfeat = gate + (size_t)N_NODE * HDH;            // 2048*384 f32
    u16*   yb    = (u16*)(gfeat + (size_t)N_NODE * HDH);   // 2048*256 u16
    u16*   WT    = yb + (size_t)N_NODE * D;                // 768*1280 u16
    u16*   WT2   = WT + (size_t)KVN * D_SEQ;               // 768*256 u16
    u16*   Qb    = WT2 + (size_t)QGN * D;                  // 8*2064*64 u16
    u16*   Kp    = Qb + (size_t)N_HEAD * QROWS * 64;       // 64*1024*64 u16
    u16*   VTt   = Kp + (size_t)B_GRAPH * N_HEAD * S_LEN * 64;  // 64*48*1024 u16
    u16*   embb  = VTt + (size_t)B_GRAPH * N_HEAD * 48 * S_LEN; // 8192*1280 u16
    int*   ranges = (int*)(embb + (size_t)B_GRAPH * S_LEN * D_SEQ);

    ranges_kernel<<<1, 64, 0, stream>>>(batch, ranges);
    // emb -> bf16
    tobf16_kernel<<<(B_GRAPH * S_LEN * D_SEQ) / (256 * 8), 256, 0, stream>>>(emb, embb);
    ln_kernel<<<N_NODE, 256, 0, stream>>>(node, ln_g, ln_b, yb);
    // weight transposes (coalesced via LDS tiles)
    wtr_kernel<<<dim3(D_SEQ / 32, HDH / 32), 256, 0, stream>>>(Wk, WT, D_SEQ, HDH);
    wtr_kernel<<<dim3(D_SEQ / 32, HDH / 32), 256, 0, stream>>>(Wv, WT + (size_t)HDH * D_SEQ, D_SEQ, HDH);
    wtr_kernel<<<dim3(D / 32, HDH / 32), 256, 0, stream>>>(Wq, WT2, D, HDH);
    wtr_kernel<<<dim3(D / 32, HDH / 32), 256, 0, stream>>>(Wg, WT2 + (size_t)HDH * D, D, HDH);
    // zero pads (Qb rows/cols, Kp d=48..63)
    (void)hipMemsetAsync(Qb, 0, (size_t)N_HEAD * QROWS * 64 * 2, stream);
    (void)hipMemsetAsync(Kp, 0, (size_t)B_GRAPH * N_HEAD * S_LEN * 64 * 2, stream);
    // fused K|V projection (m97-style, XCD-swizzled)
    kv_gemm<<<384, 256, 0, stream>>>(embb, WT, Kp, VTt);
    // fused Q|gate projection
    qg_gemm<<<dim3(QGN / 128, N_NODE / 128), 256, 0, stream>>>(
        yb, WT2, bg, Qb, gate);
    // attention (b fastest -> XCD locality)
    attn_mfma<<<dim3(B_GRAPH, N_HEAD, 32), 256, 0, stream>>>(
        Qb, Kp, VTt, mask, gate, ranges, gfeat);
    // out = node + gfeat @ Wback + bback
    gemm64<<<dim3(D / 64, N_NODE / 64), 256, 0, stream>>>(
        gfeat, Wback, out, N_NODE, D, HDH, bback, node);
}

// Round 7
// 254.032 us; speedup vs baseline: 2.9599x; 1.0460x over previous
//
#include <hip/hip_runtime.h>
#include <hip/hip_bf16.h>
#include <math.h>

#define D 256
#define D_SEQ 1280
#define D_HEAD 48
#define N_HEAD 8
#define HDH 384        // N_HEAD * D_HEAD
#define N_NODE 2048
#define B_GRAPH 8
#define S_LEN 1024
#define LN_EPS 1e-5f
#define INV_SCALE 0.14433756729740643f   // 1/sqrt(48)
#define QSCALE (0.14433756729740643f * 1.4426950408889634f)  // 1/sqrt(48)*log2(e)
#define KVN 768        // fused K|V gemm output width
#define QGN 768        // fused Q|gate gemm output width
#define QROWS (N_NODE + 16)              // padded Q rows per head
#define NWL 136        // max worklist entries: 2048/16 + 8

typedef unsigned short u16;
typedef __attribute__((ext_vector_type(8))) short short8;
typedef __attribute__((ext_vector_type(4))) short short4v;
typedef __attribute__((ext_vector_type(4))) unsigned short ushort4v;
typedef __attribute__((ext_vector_type(4))) float floatx4;

__device__ __forceinline__ u16 f2bf(float f) {
    unsigned int x = __float_as_uint(f);
    x += 0x7fff + ((x >> 16) & 1);      // RNE to bf16
    return (u16)(x >> 16);
}

// async 16B-per-lane global->LDS DMA (wave-uniform LDS base + lane*16B)
__device__ __forceinline__ void load_lds16(const u16* g, u16* lds) {
    __builtin_amdgcn_global_load_lds(
        (const __attribute__((address_space(1))) unsigned int*)g,
        (__attribute__((address_space(3))) unsigned int*)lds, 16, 0, 0);
}

// ---------------------------------------------------------------------------
// ranges + compact tile worklist. wl entry = (b<<16)|n0, -1 past end.
// ---------------------------------------------------------------------------
__global__ void ranges_kernel(const int* __restrict__ batch, int* __restrict__ ranges,
                              int* __restrict__ wl) {
    int t = threadIdx.x;
    if (t <= B_GRAPH) {
        int lo = 0, hi = N_NODE;
        while (lo < hi) {
            int mid = (lo + hi) >> 1;
            if (batch[mid] < t) lo = mid + 1; else hi = mid;
        }
        ranges[t] = lo;
    }
    __syncthreads();
    int tot = 0;
    #pragma unroll
    for (int bb = 0; bb < B_GRAPH; ++bb)
        tot += (ranges[bb + 1] - ranges[bb] + 15) >> 4;
    if (t < B_GRAPH) {
        int off = 0;
        for (int bb = 0; bb < t; ++bb)
            off += (ranges[bb + 1] - ranges[bb] + 15) >> 4;
        const int s = ranges[t];
        const int ntile = (ranges[t + 1] - s + 15) >> 4;
        for (int i = 0; i < ntile; ++i) wl[off + i] = (t << 16) | (s + i * 16);
    } else {
        for (int i = tot + (t - B_GRAPH); i < NWL; i += 64 - B_GRAPH) wl[i] = -1;
    }
}

// ---------------------------------------------------------------------------
// emb fp32 -> bf16
// ---------------------------------------------------------------------------
__global__ __launch_bounds__(256)
void tobf16_kernel(const float* __restrict__ in, u16* __restrict__ out) {
    const size_t i = ((size_t)blockIdx.x * 256 + threadIdx.x) * 8;
    const float4 a = *(const float4*)&in[i];
    const float4 b = *(const float4*)&in[i + 4];
    union { u16 u[8]; int4 v; } p;
    p.u[0]=f2bf(a.x); p.u[1]=f2bf(a.y); p.u[2]=f2bf(a.z); p.u[3]=f2bf(a.w);
    p.u[4]=f2bf(b.x); p.u[5]=f2bf(b.y); p.u[6]=f2bf(b.z); p.u[7]=f2bf(b.w);
    *(int4*)&out[i] = p.v;
}

// ---------------------------------------------------------------------------
// layernorm -> bf16
// ---------------------------------------------------------------------------
__global__ __launch_bounds__(256)
void ln_kernel(const float* __restrict__ node, const float* __restrict__ g,
               const float* __restrict__ b, u16* __restrict__ yb) {
    int n = blockIdx.x, t = threadIdx.x;
    float x = node[n * D + t];
    float s = x, sq = x * x;
    #pragma unroll
    for (int o = 32; o > 0; o >>= 1) {
        s  += __shfl_down(s, o);
        sq += __shfl_down(sq, o);
    }
    __shared__ float ss[4], sqs[4];
    if ((t & 63) == 0) { ss[t >> 6] = s; sqs[t >> 6] = sq; }
    __syncthreads();
    float S  = ss[0] + ss[1] + ss[2] + ss[3];
    float SQ = sqs[0] + sqs[1] + sqs[2] + sqs[3];
    float mu  = S * (1.f / D);
    float var = SQ * (1.f / D) - mu * mu;
    float inv = rsqrtf(var + LN_EPS);
    yb[n * D + t] = f2bf((x - mu) * inv * g[t] + b[t]);
}

// ---------------------------------------------------------------------------
// LDS-tiled transpose+convert: W[K][Ncols] fp32 -> WTo[Ncols][K] bf16
// ---------------------------------------------------------------------------
__global__ __launch_bounds__(256)
void wtr_kernel(const float* __restrict__ W, u16* __restrict__ WTo,
                int K, int Ncols) {
    __shared__ float tile[32][33];
    const int k0 = blockIdx.x * 32, n0 = blockIdx.y * 32;
    const int tx = threadIdx.x & 31, ty = threadIdx.x >> 5;
    #pragma unroll
    for (int i = 0; i < 32; i += 8)
        tile[ty + i][tx] = W[(size_t)(k0 + ty + i) * Ncols + n0 + tx];
    __syncthreads();
    #pragma unroll
    for (int i = 0; i < 32; i += 8)
        WTo[(size_t)(n0 + ty + i) * K + k0 + tx] = f2bf(tile[tx][ty + i]);
}

// ---------------------------------------------------------------------------
// fused K|V projection (m97-style, XCD-swizzled) — round-6, unchanged
// ---------------------------------------------------------------------------
__global__ __launch_bounds__(256)
void kv_gemm(const u16* __restrict__ A, const u16* __restrict__ WT,
             u16* __restrict__ Kp, u16* __restrict__ VTt) {
    __shared__ __align__(16) u16 As[128 * 32];   // [kb][row][8]
    __shared__ __align__(16) u16 Bs[128 * 32];
    const int tid = threadIdx.x;
    const int lane = tid & 63, wave = tid >> 6;
    const int glin = blockIdx.x;
    const int xcd = glin & 7, rest = glin >> 3;
    const int m0 = (xcd + 8 * (rest / 6)) * 128;
    const int n0 = (rest % 6) * 128;
    const int wm = (wave >> 1) * 64, wn = (wave & 1) * 64;
    const int lm = lane & 15, lq = lane >> 4;

    floatx4 acc[4][4] = {};

    u16* asb = &As[wave * 1024];
    u16* bsb = &Bs[wave * 1024];
    const u16* ag = &A[(size_t)(m0 + lane) * D_SEQ + wave * 8];
    const u16* bg = &WT[(size_t)(n0 + lane) * D_SEQ + wave * 8];

    for (int k0 = 0; k0 < D_SEQ; k0 += 32) {
        __syncthreads();
        load_lds16(ag + k0, asb);
        load_lds16(ag + (size_t)64 * D_SEQ + k0, asb + 512);
        load_lds16(bg + k0, bsb);
        load_lds16(bg + (size_t)64 * D_SEQ + k0, bsb + 512);
        __syncthreads();

        short8 af[4], bfr[4];
        #pragma unroll
        for (int i = 0; i < 4; ++i)
            af[i] = *(const short8*)&As[lq * 1024 + (wm + i * 16 + lm) * 8];
        #pragma unroll
        for (int i = 0; i < 4; ++i)
            bfr[i] = *(const short8*)&Bs[lq * 1024 + (wn + i * 16 + lm) * 8];
        #pragma unroll
        for (int i = 0; i < 4; ++i)
            #pragma unroll
            for (int j = 0; j < 4; ++j)
                acc[i][j] = __builtin_amdgcn_mfma_f32_16x16x32_bf16(
                    af[i], bfr[j], acc[i][j], 0, 0, 0);
    }

    #pragma unroll
    for (int i = 0; i < 4; ++i) {
        const int mrow = m0 + wm + i * 16 + lq * 4;
        const int bb = mrow >> 10, s = mrow & 1023;
        #pragma unroll
        for (int j = 0; j < 4; ++j) {
            const int n = n0 + wn + j * 16 + lm;
            if (n < HDH) {
                const int hh = n / 48, dd = n - hh * 48;
                u16* kp = &Kp[(((size_t)(bb * N_HEAD + hh)) * S_LEN + s) * 64 + dd];
                kp[0]   = f2bf(acc[i][j][0]);
                kp[64]  = f2bf(acc[i][j][1]);
                kp[128] = f2bf(acc[i][j][2]);
                kp[192] = f2bf(acc[i][j][3]);
            } else {
                const int nv = n - HDH;
                const int hh = nv / 48, dd = nv - hh * 48;
                ushort4v pk;
                pk[0] = f2bf(acc[i][j][0]); pk[1] = f2bf(acc[i][j][1]);
                pk[2] = f2bf(acc[i][j][2]); pk[3] = f2bf(acc[i][j][3]);
                *(ushort4v*)&VTt[(((size_t)(bb * N_HEAD + hh)) * 48 + dd) * S_LEN + s] = pk;
            }
        }
    }
}

// ---------------------------------------------------------------------------
// fused Q|gate projection. Q scale now folds log2(e) for exp2-softmax.
// ---------------------------------------------------------------------------
__global__ __launch_bounds__(256)
void qg_gemm(const u16* __restrict__ Ab, const u16* __restrict__ WT2,
             const float* __restrict__ bg, u16* __restrict__ Qb,
             float* __restrict__ gate) {
    __shared__ __align__(16) u16 As[128 * 32];
    __shared__ __align__(16) u16 Bs[128 * 32];
    const int tid = threadIdx.x;
    const int lane = tid & 63, wave = tid >> 6;
    const int wm = (wave >> 1) * 64, wn = (wave & 1) * 64;
    const int m0 = blockIdx.y * 128, n0 = blockIdx.x * 128;
    const int lm = lane & 15, lq = lane >> 4;

    floatx4 acc[4][4] = {};
    const int sr = tid >> 2;
    const int sc = (tid & 3) * 8;

    for (int k0 = 0; k0 < D; k0 += 32) {
        const int4 a0 = *(const int4*)&Ab[(size_t)(m0 + sr) * D + k0 + sc];
        const int4 a1 = *(const int4*)&Ab[(size_t)(m0 + sr + 64) * D + k0 + sc];
        const int4 b0 = *(const int4*)&WT2[(size_t)(n0 + sr) * D + k0 + sc];
        const int4 b1 = *(const int4*)&WT2[(size_t)(n0 + sr + 64) * D + k0 + sc];
        __syncthreads();
        *(int4*)&As[sr * 32 + sc] = a0;
        *(int4*)&As[(sr + 64) * 32 + sc] = a1;
        *(int4*)&Bs[sr * 32 + sc] = b0;
        *(int4*)&Bs[(sr + 64) * 32 + sc] = b1;
        __syncthreads();

        short8 af[4], bfr[4];
        #pragma unroll
        for (int i = 0; i < 4; ++i)
            af[i] = *(const short8*)&As[(wm + i * 16 + lm) * 32 + lq * 8];
        #pragma unroll
        for (int i = 0; i < 4; ++i)
            bfr[i] = *(const short8*)&Bs[(wn + i * 16 + lm) * 32 + lq * 8];
        #pragma unroll
        for (int i = 0; i < 4; ++i)
            #pragma unroll
            for (int j = 0; j < 4; ++j)
                acc[i][j] = __builtin_amdgcn_mfma_f32_16x16x32_bf16(
                    af[i], bfr[j], acc[i][j], 0, 0, 0);
    }

    #pragma unroll
    for (int i = 0; i < 4; ++i) {
        const int mb = m0 + wm + i * 16 + lq * 4;
        #pragma unroll
        for (int j = 0; j < 4; ++j) {
            const int n = n0 + wn + j * 16 + lm;
            #pragma unroll
            for (int r = 0; r < 4; ++r) {
                const int m = mb + r;
                const float v = acc[i][j][r];
                if (n < HDH) {
                    const int hh = n / 48, dd = n - hh * 48;
                    Qb[((size_t)hh * QROWS + m) * 64 + dd] = f2bf(v * QSCALE);
                } else {
                    const int ng = n - HDH;
                    gate[(size_t)m * HDH + ng] = 1.f / (1.f + __expf(-(v + bg[ng])));
                }
            }
        }
    }
}

// ---------------------------------------------------------------------------
// back-projection: out[2048][256] = node + gfeatb[2048][384] @ WbT[256][384]^T + b
// bf16 MFMA, 128x128 tile, qg-style staging.
// ---------------------------------------------------------------------------
__global__ __launch_bounds__(256)
void back_gemm(const u16* __restrict__ Ab, const u16* __restrict__ Bt,
               const float* __restrict__ bias, const float* __restrict__ resid,
               float* __restrict__ C) {
    __shared__ __align__(16) u16 As[128 * 32];
    __shared__ __align__(16) u16 Bs[128 * 32];
    const int tid = threadIdx.x;
    const int lane = tid & 63, wave = tid >> 6;
    const int wm = (wave >> 1) * 64, wn = (wave & 1) * 64;
    const int m0 = blockIdx.y * 128, n0 = blockIdx.x * 128;
    const int lm = lane & 15, lq = lane >> 4;

    floatx4 acc[4][4] = {};
    const int sr = tid >> 2;
    const int sc = (tid & 3) * 8;

    for (int k0 = 0; k0 < HDH; k0 += 32) {
        const int4 a0 = *(const int4*)&Ab[(size_t)(m0 + sr) * HDH + k0 + sc];
        const int4 a1 = *(const int4*)&Ab[(size_t)(m0 + sr + 64) * HDH + k0 + sc];
        const int4 b0 = *(const int4*)&Bt[(size_t)(n0 + sr) * HDH + k0 + sc];
        const int4 b1 = *(const int4*)&Bt[(size_t)(n0 + sr + 64) * HDH + k0 + sc];
        __syncthreads();
        *(int4*)&As[sr * 32 + sc] = a0;
        *(int4*)&As[(sr + 64) * 32 + sc] = a1;
        *(int4*)&Bs[sr * 32 + sc] = b0;
        *(int4*)&Bs[(sr + 64) * 32 + sc] = b1;
        __syncthreads();

        short8 af[4], bfr[4];
        #pragma unroll
        for (int i = 0; i < 4; ++i)
            af[i] = *(const short8*)&As[(wm + i * 16 + lm) * 32 + lq * 8];
        #pragma unroll
        for (int i = 0; i < 4; ++i)
            bfr[i] = *(const short8*)&Bs[(wn + i * 16 + lm) * 32 + lq * 8];
        #pragma unroll
        for (int i = 0; i < 4; ++i)
            #pragma unroll
            for (int j = 0; j < 4; ++j)
                acc[i][j] = __builtin_amdgcn_mfma_f32_16x16x32_bf16(
                    af[i], bfr[j], acc[i][j], 0, 0, 0);
    }

    #pragma unroll
    for (int i = 0; i < 4; ++i) {
        const int mb = m0 + wm + i * 16 + lq * 4;
        #pragma unroll
        for (int j = 0; j < 4; ++j) {
            const int n = n0 + wn + j * 16 + lm;
            #pragma unroll
            for (int r = 0; r < 4; ++r) {
                const int m = mb + r;
                C[(size_t)m * D + n] = acc[i][j][r] + bias[n] + resid[(size_t)m * D + n];
            }
        }
    }
}

// ---------------------------------------------------------------------------
// MFMA flash attention, no-max exp2 softmax, worklist grid, bf16 output.
// Block = one 16-node tile (from wl) x head; 4 waves partition S (256 each).
// ---------------------------------------------------------------------------
__global__ __launch_bounds__(256)
void attn_mfma(const u16* __restrict__ Qb, const u16* __restrict__ Kp,
               const u16* __restrict__ VTt, const int* __restrict__ mask,
               const float* __restrict__ gate, const int* __restrict__ ranges,
               const int* __restrict__ wl, u16* __restrict__ gfeatb) {
    const int e = wl[blockIdx.x];
    if (e < 0) return;
    const int b = e >> 16, n0 = e & 0xffff;
    const int h = blockIdx.y;
    const int nend = ranges[b + 1];
    const int NT = min(16, nend - n0);

    const int tid = threadIdx.x;
    const int wave = tid >> 6, lane = tid & 63;
    const int lm = lane & 15, lq = lane >> 4;
    const int bh = b * N_HEAD + h;

    const u16* qrow = &Qb[((size_t)h * QROWS + n0 + lm) * 64];
    const short8 qf0 = *(const short8*)&qrow[lq * 8];
    const short8 qf1 = *(const short8*)&qrow[32 + lq * 8];

    const u16* kbase = &Kp[(size_t)bh * S_LEN * 64];
    const u16* vbase = &VTt[(size_t)bh * 48 * S_LEN];
    const int* mrow = &mask[b * S_LEN];

    float l_i = 0.f;
    floatx4 acc0 = {}, acc1 = {}, acc2 = {};

    const int sbase = wave * 256;
    const u16* kr0 = &kbase[(size_t)(sbase + lm) * 64];
    short8 nkf0 = *(const short8*)&kr0[lq * 8];
    short8 nkf1 = *(const short8*)&kr0[32 + lq * 8];
    int4 nmv = *(const int4*)&mrow[sbase + lq * 4];
    short4v nvf0 = *(const short4v*)&vbase[(size_t)lm * S_LEN + sbase + lq * 4];
    short4v nvf1 = *(const short4v*)&vbase[(size_t)(16 + lm) * S_LEN + sbase + lq * 4];
    short4v nvf2 = *(const short4v*)&vbase[(size_t)(32 + lm) * S_LEN + sbase + lq * 4];

    for (int t = 0; t < 16; ++t) {
        const short8 kf0 = nkf0, kf1 = nkf1;
        const int4 mv = nmv;
        const short4v vf0 = nvf0, vf1 = nvf1, vf2 = nvf2;
        if (t < 15) {
            const int s1 = sbase + (t + 1) * 16;
            const u16* kr = &kbase[(size_t)(s1 + lm) * 64];
            nkf0 = *(const short8*)&kr[lq * 8];
            nkf1 = *(const short8*)&kr[32 + lq * 8];
            nmv = *(const int4*)&mrow[s1 + lq * 4];
            nvf0 = *(const short4v*)&vbase[(size_t)lm * S_LEN + s1 + lq * 4];
            nvf1 = *(const short4v*)&vbase[(size_t)(16 + lm) * S_LEN + s1 + lq * 4];
            nvf2 = *(const short4v*)&vbase[(size_t)(32 + lm) * S_LEN + s1 + lq * 4];
        }

        floatx4 st = {};
        st = __builtin_amdgcn_mfma_f32_16x16x32_bf16(kf0, qf0, st, 0, 0, 0);
        st = __builtin_amdgcn_mfma_f32_16x16x32_bf16(kf1, qf1, st, 0, 0, 0);

        // scores already in log2 domain (QSCALE folds log2 e); no-max softmax
        const float p0 = mv.x > 0 ? exp2f(st[0]) : 0.f;
        const float p1 = mv.y > 0 ? exp2f(st[1]) : 0.f;
        const float p2 = mv.z > 0 ? exp2f(st[2]) : 0.f;
        const float p3 = mv.w > 0 ? exp2f(st[3]) : 0.f;
        l_i += (p0 + p1) + (p2 + p3);

        union { __hip_bfloat162 h2[2]; short4v v; } pu;
        pu.h2[0] = __float22bfloat162_rn(make_float2(p0, p1));
        pu.h2[1] = __float22bfloat162_rn(make_float2(p2, p3));

        acc0 = __builtin_amdgcn_mfma_f32_16x16x16bf16_1k(vf0, pu.v, acc0, 0, 0, 0);
        acc1 = __builtin_amdgcn_mfma_f32_16x16x16bf16_1k(vf1, pu.v, acc1, 0, 0, 0);
        acc2 = __builtin_amdgcn_mfma_f32_16x16x16bf16_1k(vf2, pu.v, acc2, 0, 0, 0);
    }

    // per-node l within this wave
    l_i += __shfl_xor(l_i, 16);
    l_i += __shfl_xor(l_i, 32);

    // cross-wave plain sum
    __shared__ float sl[4][64];
    __shared__ float sacc[4][3][4][64];
    sl[wave][lane] = l_i;
    #pragma unroll
    for (int r = 0; r < 4; ++r) {
        sacc[wave][0][r][lane] = acc0[r];
        sacc[wave][1][r][lane] = acc1[r];
        sacc[wave][2][r][lane] = acc2[r];
    }
    __syncthreads();
    if (wave < 3 && lm < NT) {
        const int dt = wave;
        const float L = sl[0][lane] + sl[1][lane] + sl[2][lane] + sl[3][lane];
        const float invl = 1.f / (L + 1e-9f);
        const size_t o = (size_t)(n0 + lm) * HDH + h * 48 + dt * 16 + lq * 4;
        const float4 g4 = *(const float4*)&gate[o];
        const float o0 = (sacc[0][dt][0][lane] + sacc[1][dt][0][lane] +
                          sacc[2][dt][0][lane] + sacc[3][dt][0][lane]) * invl * g4.x;
        const float o1 = (sacc[0][dt][1][lane] + sacc[1][dt][1][lane] +
                          sacc[2][dt][1][lane] + sacc[3][dt][1][lane]) * invl * g4.y;
        const float o2 = (sacc[0][dt][2][lane] + sacc[1][dt][2][lane] +
                          sacc[2][dt][2][lane] + sacc[3][dt][2][lane]) * invl * g4.z;
        const float o3 = (sacc[0][dt][3][lane] + sacc[1][dt][3][lane] +
                          sacc[2][dt][3][lane] + sacc[3][dt][3][lane]) * invl * g4.w;
        union { __hip_bfloat162 h2[2]; ushort4v v; } r2;
        r2.h2[0] = __float22bfloat162_rn(make_float2(o0, o1));
        r2.h2[1] = __float22bfloat162_rn(make_float2(o2, o3));
        *(ushort4v*)&gfeatb[o] = r2.v;
    }
}

// ---------------------------------------------------------------------------
extern "C" void kernel_launch(void* const* d_in, const int* in_sizes, int n_in,
                              void* d_out, int out_size, void* d_ws, size_t ws_size,
                              hipStream_t stream) {
    const float* node  = (const float*)d_in[0];
    const float* emb   = (const float*)d_in[1];
    const int*   mask  = (const int*)d_in[2];
    const int*   batch = (const int*)d_in[3];
    const float* ln_g  = (const float*)d_in[4];
    const float* ln_b  = (const float*)d_in[5];
    const float* Wq    = (const float*)d_in[6];
    const float* Wk    = (const float*)d_in[7];
    const float* Wv    = (const float*)d_in[8];
    const float* Wg    = (const float*)d_in[9];
    const float* bg    = (const float*)d_in[10];
    const float* Wback = (const float*)d_in[11];
    const float* bback = (const float*)d_in[12];
    float* out = (float*)d_out;

    float* ws    = (float*)d_ws;
    float* gate  = ws;                                     // 2048*384 f32
    u16*   gfeatb = (u16*)(gate + (size_t)N_NODE * HDH);   // 2048*384 u16
    u16*   yb    = gfeatb + (size_t)N_NODE * HDH;          // 2048*256 u16
    u16*   WT    = yb + (size_t)N_NODE * D;                // 768*1280 u16
    u16*   WT2   = WT + (size_t)KVN * D_SEQ;               // 768*256 u16
    u16*   WbT   = WT2 + (size_t)QGN * D;                  // 256*384 u16
    u16*   Qb    = WbT + (size_t)D * HDH;                  // 8*2064*64 u16
    u16*   Kp    = Qb + (size_t)N_HEAD * QROWS * 64;       // 64*1024*64 u16
    u16*   VTt   = Kp + (size_t)B_GRAPH * N_HEAD * S_LEN * 64;  // 64*48*1024 u16
    u16*   embb  = VTt + (size_t)B_GRAPH * N_HEAD * 48 * S_LEN; // 8192*1280 u16
    int*   ranges = (int*)(embb + (size_t)B_GRAPH * S_LEN * D_SEQ);
    int*   wl    = ranges + 16;

    ranges_kernel<<<1, 64, 0, stream>>>(batch, ranges, wl);
    tobf16_kernel<<<(B_GRAPH * S_LEN * D_SEQ) / (256 * 8), 256, 0, stream>>>(emb, embb);
    ln_kernel<<<N_NODE, 256, 0, stream>>>(node, ln_g, ln_b, yb);
    wtr_kernel<<<dim3(D_SEQ / 32, HDH / 32), 256, 0, stream>>>(Wk, WT, D_SEQ, HDH);
    wtr_kernel<<<dim3(D_SEQ / 32, HDH / 32), 256, 0, stream>>>(Wv, WT + (size_t)HDH * D_SEQ, D_SEQ, HDH);
    wtr_kernel<<<dim3(D / 32, HDH / 32), 256, 0, stream>>>(Wq, WT2, D, HDH);
    wtr_kernel<<<dim3(D / 32, HDH / 32), 256, 0, stream>>>(Wg, WT2 + (size_t)HDH * D, D, HDH);
    wtr_kernel<<<dim3(HDH / 32, D / 32), 256, 0, stream>>>(Wback, WbT, HDH, D);
    (void)hipMemsetAsync(Qb, 0, (size_t)N_HEAD * QROWS * 64 * 2, stream);
    (void)hipMemsetAsync(Kp, 0, (size_t)B_GRAPH * N_HEAD * S_LEN * 64 * 2, stream);
    kv_gemm<<<384, 256, 0, stream>>>(embb, WT, Kp, VTt);
    qg_gemm<<<dim3(QGN / 128, N_NODE / 128), 256, 0, stream>>>(
        yb, WT2, bg, Qb, gate);
    attn_mfma<<<dim3(NWL, N_HEAD), 256, 0, stream>>>(
        Qb, Kp, VTt, mask, gate, ranges, wl, gfeatb);
    back_gemm<<<dim3(D / 128, N_NODE / 128), 256, 0, stream>>>(
        gfeatb, WbT, bback, node, out);
}